// Round 3
// baseline (606.894 us; speedup 1.0000x reference)
//
#include <hip/hip_runtime.h>

#define B_SZ 2

__device__ __forceinline__ int rfl(int x) { return __builtin_amdgcn_readfirstlane(x); }
__device__ __forceinline__ float leaky(float v) { return v >= 0.f ? v : 0.1f * v; }

// ---------------------------------------------------------------- KNN ----
__launch_bounds__(256)
__global__ void pack_kernel(const float* __restrict__ xyz, float4* __restrict__ out, int N)
{
  int b = blockIdx.y;
  int i = blockIdx.x * 256 + threadIdx.x;
  if (i >= N) return;
  const float* p = xyz + (size_t)b * 3 * N;
  float x = p[i], y = p[N + i], z = p[2 * N + i];
  out[(size_t)b * N + i] = make_float4(x, y, z, x * x + y * y + z * z);
}

// One wave per query. Top-16 kept lane-distributed (lanes 0..15, ascending).
__launch_bounds__(256)
__global__ void knn_wave_kernel(const float4* __restrict__ pk, const float* __restrict__ q,
                                int* __restrict__ idx, int N)
{
  __shared__ float sx[1024], sy[1024], sz[1024], sw[1024];
  int b = blockIdx.y;
  int lane = threadIdx.x & 63, wav = rfl(threadIdx.x >> 6);
  int qi = blockIdx.x * 4 + wav;
  const float* qb = q + (size_t)b * 3 * N;
  float qx = qb[qi], qy = qb[N + qi], qz = qb[2 * N + qi];
  float qq = qx * qx + qy * qy + qz * qz;
  float bd = 3.0e38f;
  int   bi = 0;
  float thr = 3.0e38f;
  const float4* pb = pk + (size_t)b * N;
  for (int ch = 0; ch < N; ch += 1024) {
    __syncthreads();
    for (int i = threadIdx.x; i < 1024; i += 256) {
      float4 v = pb[ch + i];
      sx[i] = v.x; sy[i] = v.y; sz[i] = v.z; sw[i] = v.w;
    }
    __syncthreads();
    for (int sub = 0; sub < 1024; sub += 64) {
      int c = sub + lane;
      float dl = (qq + sw[c]) - 2.0f * (qx * sx[c] + qy * sy[c] + qz * sz[c]);
      unsigned long long qm = __ballot(dl < thr);
      while (qm) {
        int l = __ffsll(qm) - 1;
        qm &= qm - 1;
        float dc = __shfl(dl, l);
        unsigned long long rm = __ballot(lane < 16 && bd <= dc);
        int pos = __popcll(rm);
        if (pos < 16) {
          int ic = ch + sub + l;
          float pbd = __shfl(bd, lane - 1);
          int   pbi = __shfl(bi, lane - 1);
          if (lane < 16) {
            if (lane == pos)      { bd = dc;  bi = ic; }
            else if (lane > pos)  { bd = pbd; bi = pbi; }
          }
          thr = __shfl(bd, 15);
        }
      }
    }
  }
  if (lane < 16) idx[((size_t)b * N + qi) * 16 + lane] = bi;
}

// --------------------------------------------------------- projections ----
// out[b][n][oo+lane] = bias + sum_segs W[lane, wc+c]*f * seg[b,c,(n)]
// W staged compacted+prescaled into LDS; x loads are wave-uniform (scalar).
__device__ __forceinline__ void seg_accumL(const float* __restrict__ p, int cnt,
    const float* __restrict__ WL, int sC, int sN, long n0, float acc[4])
{
#pragma unroll 4
  for (int c = 0; c < cnt; ++c) {
    float w = WL[c];
    const float* pp = p + (size_t)c * sC + (size_t)n0 * sN;
#pragma unroll
    for (int m = 0; m < 4; ++m)
      acc[m] = fmaf(w, pp[(size_t)m * sN], acc[m]);
  }
}

template<int WP>
__launch_bounds__(256)
__global__ void proj_kernel(
    const float* __restrict__ W0, const float* __restrict__ W1,
    const float* __restrict__ b0, const float* __restrict__ b1,
    float* __restrict__ out0, float* __restrict__ out1,
    int oo0, int oo1, int OUTS, int wld, int N,
    const float* __restrict__ s0, int c0, int w0, int sC0, int sN0, float f0,
    const float* __restrict__ s1, int c1, int w1, int sC1, int sN1, float f1,
    const float* __restrict__ s2, int c2, int w2, int sC2, int sN2, float f2,
    const float* __restrict__ s3, int c3, int w3, int sC3, int sN3, float f3)
{
  __shared__ float Wl[64 * WP];
  const int z = blockIdx.z;
  const float* W = z ? W1 : W0;
  const float* bias = z ? b1 : b0;
  float* out = z ? out1 : out0;
  const int oo = z ? oo1 : oo0;
  const int b = blockIdx.y;
  const int lane = threadIdx.x & 63;
  const int wav = rfl(threadIdx.x >> 6);
  int lco = 0;
  if (c0 > 0) {
    for (int r = wav; r < 64; r += 4)
      for (int c = lane; c < c0; c += 64)
        Wl[r * WP + lco + c] = W[(size_t)r * wld + w0 + c] * f0;
    lco += c0;
  }
  if (c1 > 0) {
    for (int r = wav; r < 64; r += 4)
      for (int c = lane; c < c1; c += 64)
        Wl[r * WP + lco + c] = W[(size_t)r * wld + w1 + c] * f1;
    lco += c1;
  }
  if (c2 > 0) {
    for (int r = wav; r < 64; r += 4)
      for (int c = lane; c < c2; c += 64)
        Wl[r * WP + lco + c] = W[(size_t)r * wld + w2 + c] * f2;
    lco += c2;
  }
  if (c3 > 0) {
    for (int r = wav; r < 64; r += 4)
      for (int c = lane; c < c3; c += 64)
        Wl[r * WP + lco + c] = W[(size_t)r * wld + w3 + c] * f3;
    lco += c3;
  }
  __syncthreads();
  const long n0 = ((long)blockIdx.x * 4 + wav) * 4;
  float bv = bias ? bias[oo + lane] : 0.0f;
  float acc[4] = {bv, bv, bv, bv};
  const float* WL = &Wl[lane * WP];
  lco = 0;
  if (c0 > 0) { seg_accumL(s0 + (size_t)b * c0 * N, c0, WL + lco, sC0, sN0, n0, acc); lco += c0; }
  if (c1 > 0) { seg_accumL(s1 + (size_t)b * c1 * N, c1, WL + lco, sC1, sN1, n0, acc); lco += c1; }
  if (c2 > 0) { seg_accumL(s2 + (size_t)b * c2 * N, c2, WL + lco, sC2, sN2, n0, acc); lco += c2; }
  if (c3 > 0) { seg_accumL(s3 + (size_t)b * c3 * N, c3, WL + lco, sC3, sN3, n0, acc); lco += c3; }
#pragma unroll
  for (int m = 0; m < 4; ++m)
    out[((size_t)b * N + n0 + m) * OUTS + oo + lane] = acc[m];
}

// ------------------------------------------------------------- groupnorm ----
__launch_bounds__(256)
__global__ void gn1_stats_kernel(const float* __restrict__ G1, const float* __restrict__ xyz0,
    const float* __restrict__ fw1, const int* __restrict__ idx0,
    float* __restrict__ stats1, int N)
{
  __shared__ float red[4][4][2];
  int b = blockIdx.y;
  int lane = threadIdx.x & 63, wav = rfl(threadIdx.x >> 6);
  float wg0 = fw1[lane * 6 + 3], wg1 = fw1[lane * 6 + 4], wg2 = fw1[lane * 6 + 5];
  const float* xb = xyz0 + (size_t)b * 3 * N;
  float sum = 0.f, sq = 0.f;
  for (int n = blockIdx.x * 4 + wav; n < N; n += gridDim.x * 4) {
    const int* ip = idx0 + ((size_t)b * N + n) * 16;
    float bx = wg0 * xb[n] + wg1 * xb[N + n] + wg2 * xb[2 * N + n];
#pragma unroll
    for (int k = 0; k < 16; ++k) {
      int m = ip[k];
      float y = G1[((size_t)b * N + m) * 64 + lane] - bx;
      sum += y; sq += y * y;
    }
  }
#pragma unroll
  for (int off = 1; off < 16; off <<= 1) {
    sum += __shfl_xor(sum, off, 64);
    sq += __shfl_xor(sq, off, 64);
  }
  int g = lane >> 4;
  if ((lane & 15) == 0) { red[wav][g][0] = sum; red[wav][g][1] = sq; }
  __syncthreads();
  if (threadIdx.x < 8) {
    int gg = threadIdx.x >> 1, s = threadIdx.x & 1;
    float v = red[0][gg][s] + red[1][gg][s] + red[2][gg][s] + red[3][gg][s];
    atomicAdd(&stats1[(b * 4 + gg) * 2 + s], v);
  }
}

__global__ void gn_finalize_kernel(const float* __restrict__ raw, float* __restrict__ mi, float cnt)
{
  int i = threadIdx.x;
  if (i < 8) {
    float s = raw[i * 2], q = raw[i * 2 + 1];
    float m = s / cnt;
    float v = q / cnt - m * m;
    mi[i * 2] = m;
    mi[i * 2 + 1] = rsqrtf(v + 1e-5f);
  }
}

// ------------------------------------------------------------- flow conv2 ----
__launch_bounds__(256)
__global__ void conv2_kernel(const float* __restrict__ G1, const float* __restrict__ xyz0,
    const float* __restrict__ fw1, const int* __restrict__ idx0,
    const float* __restrict__ fw2, const float* __restrict__ fb2,
    const float* __restrict__ fg1, const float* __restrict__ fbe1,
    const float* __restrict__ mi1, float* __restrict__ y2max, float* __restrict__ y2min,
    float* __restrict__ stats2, int N)
{
  __shared__ __align__(16) float x2[4][16][64];
  __shared__ float red[4][4][2];
  const int b = blockIdx.y;
  const int lane = threadIdx.x & 63;
  const int wav = rfl(threadIdx.x >> 6);
  float4 w[16];
#pragma unroll
  for (int i = 0; i < 16; ++i) w[i] = *(const float4*)&fw2[lane * 64 + i * 4];
  float wg0 = fw1[lane * 6 + 3], wg1 = fw1[lane * 6 + 4], wg2 = fw1[lane * 6 + 5];
  const int g = lane >> 4;
  float mu1 = mi1[(b * 4 + g) * 2], inv1 = mi1[(b * 4 + g) * 2 + 1];
  float sc1 = fg1[lane] * inv1;
  float sh1 = fbe1[lane] - mu1 * sc1;
  float fb2l = fb2[lane];
  const float* xb = xyz0 + (size_t)b * 3 * N;
  float sum = 0.f, sq = 0.f;
  for (int n = blockIdx.x * 4 + wav; n < N; n += gridDim.x * 4) {
    const int* ip = idx0 + ((size_t)b * N + n) * 16;
    float bx = wg0 * xb[n] + wg1 * xb[N + n] + wg2 * xb[2 * N + n];
#pragma unroll
    for (int k = 0; k < 16; ++k) {
      int m = ip[k];
      float y = G1[((size_t)b * N + m) * 64 + lane] - bx;
      x2[wav][k][lane] = leaky(y * sc1 + sh1);
    }
    float acc[16];
#pragma unroll
    for (int k = 0; k < 16; ++k) acc[k] = fb2l;
#pragma unroll 4
    for (int c4 = 0; c4 < 16; ++c4) {
      float4 w4 = w[c4];
#pragma unroll
      for (int k = 0; k < 16; ++k) {
        float4 x4 = *(const float4*)&x2[wav][k][c4 * 4];
        acc[k] = fmaf(w4.x, x4.x, acc[k]);
        acc[k] = fmaf(w4.y, x4.y, acc[k]);
        acc[k] = fmaf(w4.z, x4.z, acc[k]);
        acc[k] = fmaf(w4.w, x4.w, acc[k]);
      }
    }
    float mx = -3.0e38f, mn = 3.0e38f;
#pragma unroll
    for (int k = 0; k < 16; ++k) {
      mx = fmaxf(mx, acc[k]); mn = fminf(mn, acc[k]);
      sum += acc[k]; sq += acc[k] * acc[k];
    }
    y2max[((size_t)b * N + n) * 64 + lane] = mx;
    y2min[((size_t)b * N + n) * 64 + lane] = mn;
  }
#pragma unroll
  for (int off = 1; off < 16; off <<= 1) {
    sum += __shfl_xor(sum, off, 64);
    sq += __shfl_xor(sq, off, 64);
  }
  if ((lane & 15) == 0) { red[wav][g][0] = sum; red[wav][g][1] = sq; }
  __syncthreads();
  if (threadIdx.x < 8) {
    int gg = threadIdx.x >> 1, s = threadIdx.x & 1;
    float v = red[0][gg][s] + red[1][gg][s] + red[2][gg][s] + red[3][gg][s];
    atomicAdd(&stats2[(b * 4 + gg) * 2 + s], v);
  }
}

__launch_bounds__(256)
__global__ void flow_feat_kernel(const float* __restrict__ y2max, const float* __restrict__ y2min,
    const float* __restrict__ mi2, const float* __restrict__ fg2, const float* __restrict__ fbe2,
    float* __restrict__ ff, int N)
{
  size_t i = (size_t)blockIdx.x * blockDim.x + threadIdx.x;
  if (i >= (size_t)B_SZ * N * 64) return;
  int c = i & 63;
  size_t pn = i >> 6;
  int b = (int)(pn / N);
  int g = c >> 4;
  float mu = mi2[(b * 4 + g) * 2], inv = mi2[(b * 4 + g) * 2 + 1];
  float sc = fg2[c] * inv;
  float sh = fbe2[c] - mu * sc;
  float y = (sc >= 0.0f) ? y2max[i] : y2min[i];
  ff[i] = leaky(y * sc + sh);
}

// ------------------------------------------------------------------ gates ----
__launch_bounds__(256)
__global__ void gate_zr_kernel(const float* __restrict__ Sz, const float* __restrict__ Sr,
    const float* __restrict__ wz, const float* __restrict__ wr,
    const float* __restrict__ xyz0, const float* __restrict__ state,
    const int* __restrict__ idx0,
    float* __restrict__ zo, float* __restrict__ rs, int N)
{
  int b = blockIdx.y;
  int lane = threadIdx.x & 63, wav = rfl(threadIdx.x >> 6);
  float wz0 = wz[lane * 195 + 192], wz1 = wz[lane * 195 + 193], wz2 = wz[lane * 195 + 194];
  float wr0 = wr[lane * 195 + 192], wr1 = wr[lane * 195 + 193], wr2 = wr[lane * 195 + 194];
  const float* xb = xyz0 + (size_t)b * 3 * N;
  for (int n = blockIdx.x * 4 + wav; n < N; n += gridDim.x * 4) {
    const int* ip = idx0 + ((size_t)b * N + n) * 16;
    float u0 = xb[n], u1 = xb[N + n], u2 = xb[2 * N + n];
    float xz = wz0 * u0 + wz1 * u1 + wz2 * u2;
    float xr = wr0 * u0 + wr1 * u1 + wr2 * u2;
    float mz = -3.0e38f, mr = -3.0e38f;
#pragma unroll
    for (int k = 0; k < 16; ++k) {
      size_t mo = ((size_t)b * N + ip[k]) * 64 + lane;
      mz = fmaxf(mz, Sz[mo]);
      mr = fmaxf(mr, Sr[mo]);
    }
    size_t no = ((size_t)b * N + n) * 64 + lane;
    float z = 1.f / (1.f + expf(-(mz - xz)));
    float r = 1.f / (1.f + expf(-(mr - xr)));
    zo[no] = z;
    rs[no] = r * state[((size_t)b * 64 + lane) * N + n];
  }
}

__launch_bounds__(256)
__global__ void gate_q_ns_kernel(const float* __restrict__ Sq, const float* __restrict__ wq,
    const float* __restrict__ xyz0, const float* __restrict__ zo,
    const float* __restrict__ state, const int* __restrict__ idx0,
    float* __restrict__ ns, int N)
{
  int b = blockIdx.y;
  int lane = threadIdx.x & 63, wav = rfl(threadIdx.x >> 6);
  float wq0 = wq[lane * 195 + 192], wq1 = wq[lane * 195 + 193], wq2 = wq[lane * 195 + 194];
  const float* xb = xyz0 + (size_t)b * 3 * N;
  for (int n = blockIdx.x * 4 + wav; n < N; n += gridDim.x * 4) {
    const int* ip = idx0 + ((size_t)b * N + n) * 16;
    float xq = wq0 * xb[n] + wq1 * xb[N + n] + wq2 * xb[2 * N + n];
    float mq = -3.0e38f;
#pragma unroll
    for (int k = 0; k < 16; ++k)
      mq = fmaxf(mq, Sq[((size_t)b * N + ip[k]) * 64 + lane]);
    size_t no = ((size_t)b * N + n) * 64 + lane;
    float q = tanhf(mq - xq);
    float z = zo[no];
    float st = state[((size_t)b * 64 + lane) * N + n];
    ns[no] = (1.f - z) * st + z * q;
  }
}

// ------------------------------------------------------------------ align ----
__launch_bounds__(256)
__global__ void align_kernel(const float* __restrict__ U, const float* __restrict__ V,
    const float* __restrict__ wa2, const float* __restrict__ ba2,
    const float* __restrict__ ns, const int* __restrict__ idx1,
    float* __restrict__ out, int N)
{
  __shared__ __align__(16) float xk[4][16][128];
  const int b = blockIdx.y;
  const int lane = threadIdx.x & 63;
  const int wav = rfl(threadIdx.x >> 6);
  float4 w[32];
#pragma unroll
  for (int i = 0; i < 32; ++i) w[i] = *(const float4*)&wa2[lane * 128 + i * 4];
  float ba = ba2[lane];
  const int n = blockIdx.x * 4 + wav;
  const int* ip = idx1 + ((size_t)b * N + n) * 16;
  int mk[16];
#pragma unroll
  for (int k = 0; k < 16; ++k) mk[k] = ip[k];
  const float* Vp = V + ((size_t)b * N + n) * 128;
  float v0 = Vp[lane], v1 = Vp[64 + lane];
#pragma unroll
  for (int k = 0; k < 16; ++k) {
    const float* Up = U + ((size_t)b * N + mk[k]) * 128;
    xk[wav][k][lane] = leaky(Up[lane] + v0);
    xk[wav][k][64 + lane] = leaky(Up[64 + lane] + v1);
  }
  float acc[16];
#pragma unroll
  for (int k = 0; k < 16; ++k) acc[k] = ba;
#pragma unroll 2
  for (int c4 = 0; c4 < 32; ++c4) {
    float4 w4 = w[c4];
#pragma unroll
    for (int k = 0; k < 16; ++k) {
      float4 x4 = *(const float4*)&xk[wav][k][c4 * 4];
      acc[k] = fmaf(w4.x, x4.x, acc[k]);
      acc[k] = fmaf(w4.y, x4.y, acc[k]);
      acc[k] = fmaf(w4.z, x4.z, acc[k]);
      acc[k] = fmaf(w4.w, x4.w, acc[k]);
    }
  }
  float m = acc[0];
#pragma unroll
  for (int k = 1; k < 16; ++k) m = fmaxf(m, acc[k]);
  float s = 0.f;
#pragma unroll
  for (int k = 0; k < 16; ++k) { acc[k] = expf(acc[k] - m); s += acc[k]; }
  float rinv = 1.0f / s;
  float o = 0.f;
#pragma unroll
  for (int k = 0; k < 16; ++k)
    o += acc[k] * rinv * ns[((size_t)b * N + mk[k]) * 64 + lane];
  out[((size_t)b * 64 + lane) * N + n] = o;
}

// ------------------------------------------------------------------ launch ----
extern "C" void kernel_launch(void* const* d_in, const int* in_sizes, int n_in,
                              void* d_out, int out_size, void* d_ws, size_t ws_size,
                              hipStream_t stream) {
  (void)n_in; (void)out_size; (void)ws_size;
  const float* xyz0 = (const float*)d_in[0];
  const float* xyz1 = (const float*)d_in[1];
  const float* state = (const float*)d_in[2];
  const float* corr0 = (const float*)d_in[3];
  const float* feat0 = (const float*)d_in[4];
  const float* feat1 = (const float*)d_in[5];
  const float* flow0 = (const float*)d_in[6];
  const float* fw1 = (const float*)d_in[7];
  const float* fb1 = (const float*)d_in[8];
  const float* fg1 = (const float*)d_in[9];
  const float* fbe1 = (const float*)d_in[10];
  const float* fw2 = (const float*)d_in[11];
  const float* fb2 = (const float*)d_in[12];
  const float* fg2 = (const float*)d_in[13];
  const float* fbe2 = (const float*)d_in[14];
  const float* wz = (const float*)d_in[15];
  const float* bz = (const float*)d_in[16];
  const float* wr = (const float*)d_in[17];
  const float* br = (const float*)d_in[18];
  const float* wq = (const float*)d_in[19];
  const float* bq = (const float*)d_in[20];
  const float* wa1 = (const float*)d_in[21];
  const float* ba1 = (const float*)d_in[22];
  const float* wa2 = (const float*)d_in[23];
  const float* ba2 = (const float*)d_in[24];
  float* out = (float*)d_out;

  const int N = in_sizes[0] / (3 * B_SZ);  // 4096
  char* wsb = (char*)d_ws;
  size_t off = 0;
  auto take = [&](size_t bytes) -> char* {
    char* p = wsb + off;
    off += (bytes + 255) & ~(size_t)255;
    return p;
  };
  const size_t PN = (size_t)B_SZ * N;
  float* U    = (float*)take(PN * 128 * 4);
  float* V    = (float*)take(PN * 128 * 4);
  float4* pk0 = (float4*)take(PN * 4 * 4);
  int*   idx0 = (int*)  take(PN * 16 * 4);
  int*   idx1 = (int*)  take(PN * 16 * 4);
  float* G1   = (float*)take(PN * 64 * 4);
  float* y2mx = (float*)take(PN * 64 * 4);
  float* y2mn = (float*)take(PN * 64 * 4);
  float* ff   = (float*)take(PN * 64 * 4);
  float* Sz   = (float*)take(PN * 64 * 4);
  float* Sr   = (float*)take(PN * 64 * 4);
  float* Sq   = (float*)take(PN * 64 * 4);
  float* zg   = (float*)take(PN * 64 * 4);
  float* rs   = (float*)take(PN * 64 * 4);
  float* ns   = (float*)take(PN * 64 * 4);
  float* stats = (float*)take(256);
  float* raw1 = stats, *raw2 = stats + 16, *mi1 = stats + 32, *mi2 = stats + 48;

  const float* FN = nullptr;
  float* FO = nullptr;
  const float cntv = 16.0f * N * 16.0f;

  hipMemsetAsync(raw1, 0, 32 * sizeof(float), stream);

  pack_kernel<<<dim3((N + 255) / 256, B_SZ), 256, 0, stream>>>(xyz0, pk0, N);
  knn_wave_kernel<<<dim3(N / 4, B_SZ), 256, 0, stream>>>(pk0, xyz0, idx0, N);
  knn_wave_kernel<<<dim3(N / 4, B_SZ), 256, 0, stream>>>(pk0, xyz1, idx1, N);

  // G1 = fw1[:,:3]@flow0 + fw1[:,3:]@xyz0 + fb1
  proj_kernel<7><<<dim3(N / 16, B_SZ, 1), 256, 0, stream>>>(
      fw1, fw1, fb1, fb1, G1, G1, 0, 0, 64, 6, N,
      flow0, 3, 0, N, 1, 1.f,  xyz0, 3, 3, N, 1, 1.f,
      FN, 0, 0, 1, 1, 0.f,     FN, 0, 0, 1, 1, 0.f);

  gn1_stats_kernel<<<dim3(256, B_SZ), 256, 0, stream>>>(G1, xyz0, fw1, idx0, raw1, N);
  gn_finalize_kernel<<<1, 64, 0, stream>>>(raw1, mi1, cntv);
  conv2_kernel<<<dim3(512, B_SZ), 256, 0, stream>>>(G1, xyz0, fw1, idx0, fw2, fb2, fg1, fbe1,
      mi1, y2mx, y2mn, raw2, N);
  gn_finalize_kernel<<<1, 64, 0, stream>>>(raw2, mi2, cntv);
  flow_feat_kernel<<<dim3((unsigned)(PN * 64 / 256)), 256, 0, stream>>>(y2mx, y2mn, mi2, fg2, fbe2, ff, N);

  // Sz/Sr in one launch (z selects weights); segments: corr0, ff, state, xyz0
  proj_kernel<195><<<dim3(N / 16, B_SZ, 2), 256, 0, stream>>>(
      wz, wr, bz, br, Sz, Sr, 0, 0, 64, 195, N,
      corr0, 64, 0, N, 1, 1.f,   ff, 64, 64, 1, 64, 1.f,
      state, 64, 128, N, 1, 1.f, xyz0, 3, 192, N, 1, 1.f);

  gate_zr_kernel<<<dim3(256, B_SZ), 256, 0, stream>>>(Sz, Sr, wz, wr, xyz0, state, idx0, zg, rs, N);

  proj_kernel<195><<<dim3(N / 16, B_SZ, 1), 256, 0, stream>>>(
      wq, wq, bq, bq, Sq, Sq, 0, 0, 64, 195, N,
      corr0, 64, 0, N, 1, 1.f,   ff, 64, 64, 1, 64, 1.f,
      rs, 64, 128, 1, 64, 1.f,   xyz0, 3, 192, N, 1, 1.f);

  gate_q_ns_kernel<<<dim3(256, B_SZ), 256, 0, stream>>>(Sq, wq, xyz0, zg, state, idx0, ns, N);

  // U = wa1[:, :128]@feat0 + wa1[:,256:]@xyz0  (two 64-row slices via z)
  proj_kernel<131><<<dim3(N / 16, B_SZ, 2), 256, 0, stream>>>(
      wa1, wa1 + (size_t)64 * 259, FN, FN, U, U, 0, 64, 128, 259, N,
      feat0, 128, 0, N, 1, 1.f,  xyz0, 3, 256, N, 1, 1.f,
      FN, 0, 0, 1, 1, 0.f,       FN, 0, 0, 1, 1, 0.f);
  // V = wa1[:,128:256]@feat1 - wa1[:,256:]@xyz1 + ba1
  proj_kernel<131><<<dim3(N / 16, B_SZ, 2), 256, 0, stream>>>(
      wa1, wa1 + (size_t)64 * 259, ba1, ba1, V, V, 0, 64, 128, 259, N,
      feat1, 128, 128, N, 1, 1.f, xyz1, 3, 256, N, 1, -1.f,
      FN, 0, 0, 1, 1, 0.f,        FN, 0, 0, 1, 1, 0.f);

  align_kernel<<<dim3(N / 4, B_SZ), 256, 0, stream>>>(U, V, wa2, ba2, ns, idx1, out, N);
  (void)FO;
}

// Round 4
// 519.384 us; speedup vs baseline: 1.1685x; 1.1685x over previous
//
#include <hip/hip_runtime.h>

#define B_SZ 2

__device__ __forceinline__ int rfl(int x) { return __builtin_amdgcn_readfirstlane(x); }
__device__ __forceinline__ float leaky(float v) { return v >= 0.f ? v : 0.1f * v; }

// ---------------------------------------------------------------- KNN ----
__launch_bounds__(256)
__global__ void pack_kernel(const float* __restrict__ xyz, float4* __restrict__ out, int N)
{
  int b = blockIdx.y;
  int i = blockIdx.x * 256 + threadIdx.x;
  if (i >= N) return;
  const float* p = xyz + (size_t)b * 3 * N;
  float x = p[i], y = p[N + i], z = p[2 * N + i];
  out[(size_t)b * N + i] = make_float4(x, y, z, x * x + y * y + z * z);
}

// One wave per query. Top-16 kept lane-distributed (lanes 0..15, ascending).
__launch_bounds__(256)
__global__ void knn_wave_kernel(const float4* __restrict__ pk, const float* __restrict__ q,
                                int* __restrict__ idx, int N)
{
  __shared__ float sx[1024], sy[1024], sz[1024], sw[1024];
  int b = blockIdx.y;
  int lane = threadIdx.x & 63, wav = rfl(threadIdx.x >> 6);
  int qi = blockIdx.x * 4 + wav;
  const float* qb = q + (size_t)b * 3 * N;
  float qx = qb[qi], qy = qb[N + qi], qz = qb[2 * N + qi];
  float qq = qx * qx + qy * qy + qz * qz;
  float bd = 3.0e38f;
  int   bi = 0;
  float thr = 3.0e38f;
  const float4* pb = pk + (size_t)b * N;
  for (int ch = 0; ch < N; ch += 1024) {
    __syncthreads();
    for (int i = threadIdx.x; i < 1024; i += 256) {
      float4 v = pb[ch + i];
      sx[i] = v.x; sy[i] = v.y; sz[i] = v.z; sw[i] = v.w;
    }
    __syncthreads();
    for (int sub = 0; sub < 1024; sub += 64) {
      int c = sub + lane;
      float dl = (qq + sw[c]) - 2.0f * (qx * sx[c] + qy * sy[c] + qz * sz[c]);
      unsigned long long qm = __ballot(dl < thr);
      while (qm) {
        int l = __ffsll(qm) - 1;
        qm &= qm - 1;
        float dc = __shfl(dl, l);
        unsigned long long rm = __ballot(lane < 16 && bd <= dc);
        int pos = __popcll(rm);
        if (pos < 16) {
          int ic = ch + sub + l;
          float pbd = __shfl(bd, lane - 1);
          int   pbi = __shfl(bi, lane - 1);
          if (lane < 16) {
            if (lane == pos)      { bd = dc;  bi = ic; }
            else if (lane > pos)  { bd = pbd; bi = pbi; }
          }
          thr = __shfl(bd, 15);
        }
      }
    }
  }
  if (lane < 16) idx[((size_t)b * N + qi) * 16 + lane] = bi;
}

// --------------------------------------------------------- projections ----
__device__ __forceinline__ void seg_accumL(const float* __restrict__ p, int cnt,
    const float* __restrict__ WL, int sC, int sN, long n0, float acc[4])
{
#pragma unroll 4
  for (int c = 0; c < cnt; ++c) {
    float w = WL[c];
    const float* pp = p + (size_t)c * sC + (size_t)n0 * sN;
#pragma unroll
    for (int m = 0; m < 4; ++m)
      acc[m] = fmaf(w, pp[(size_t)m * sN], acc[m]);
  }
}

template<int WP>
__launch_bounds__(256)
__global__ void proj_kernel(
    const float* __restrict__ W0, const float* __restrict__ W1,
    const float* __restrict__ b0, const float* __restrict__ b1,
    float* __restrict__ out0, float* __restrict__ out1,
    int oo0, int oo1, int OUTS, int wld, int N,
    const float* __restrict__ s0, int c0, int w0, int sC0, int sN0, float f0,
    const float* __restrict__ s1, int c1, int w1, int sC1, int sN1, float f1,
    const float* __restrict__ s2, int c2, int w2, int sC2, int sN2, float f2,
    const float* __restrict__ s3, int c3, int w3, int sC3, int sN3, float f3)
{
  __shared__ float Wl[64 * WP];
  const int z = blockIdx.z;
  const float* W = z ? W1 : W0;
  const float* bias = z ? b1 : b0;
  float* out = z ? out1 : out0;
  const int oo = z ? oo1 : oo0;
  const int b = blockIdx.y;
  const int lane = threadIdx.x & 63;
  const int wav = rfl(threadIdx.x >> 6);
  int lco = 0;
  if (c0 > 0) {
    for (int r = wav; r < 64; r += 4)
      for (int c = lane; c < c0; c += 64)
        Wl[r * WP + lco + c] = W[(size_t)r * wld + w0 + c] * f0;
    lco += c0;
  }
  if (c1 > 0) {
    for (int r = wav; r < 64; r += 4)
      for (int c = lane; c < c1; c += 64)
        Wl[r * WP + lco + c] = W[(size_t)r * wld + w1 + c] * f1;
    lco += c1;
  }
  if (c2 > 0) {
    for (int r = wav; r < 64; r += 4)
      for (int c = lane; c < c2; c += 64)
        Wl[r * WP + lco + c] = W[(size_t)r * wld + w2 + c] * f2;
    lco += c2;
  }
  if (c3 > 0) {
    for (int r = wav; r < 64; r += 4)
      for (int c = lane; c < c3; c += 64)
        Wl[r * WP + lco + c] = W[(size_t)r * wld + w3 + c] * f3;
    lco += c3;
  }
  __syncthreads();
  const long n0 = ((long)blockIdx.x * 4 + wav) * 4;
  float bv = bias ? bias[oo + lane] : 0.0f;
  float acc[4] = {bv, bv, bv, bv};
  const float* WL = &Wl[lane * WP];
  lco = 0;
  if (c0 > 0) { seg_accumL(s0 + (size_t)b * c0 * N, c0, WL + lco, sC0, sN0, n0, acc); lco += c0; }
  if (c1 > 0) { seg_accumL(s1 + (size_t)b * c1 * N, c1, WL + lco, sC1, sN1, n0, acc); lco += c1; }
  if (c2 > 0) { seg_accumL(s2 + (size_t)b * c2 * N, c2, WL + lco, sC2, sN2, n0, acc); lco += c2; }
  if (c3 > 0) { seg_accumL(s3 + (size_t)b * c3 * N, c3, WL + lco, sC3, sN3, n0, acc); lco += c3; }
#pragma unroll
  for (int m = 0; m < 4; ++m)
    out[((size_t)b * N + n0 + m) * OUTS + oo + lane] = acc[m];
}

// ------------------------------------------------------------- groupnorm ----
__launch_bounds__(256)
__global__ void gn1_stats_kernel(const float* __restrict__ G1, const float* __restrict__ xyz0,
    const float* __restrict__ fw1, const int* __restrict__ idx0,
    float* __restrict__ stats1, int N)
{
  __shared__ float red[4][4][2];
  int b = blockIdx.y;
  int lane = threadIdx.x & 63, wav = rfl(threadIdx.x >> 6);
  float wg0 = fw1[lane * 6 + 3], wg1 = fw1[lane * 6 + 4], wg2 = fw1[lane * 6 + 5];
  const float* xb = xyz0 + (size_t)b * 3 * N;
  float sum = 0.f, sq = 0.f;
  for (int n = blockIdx.x * 4 + wav; n < N; n += gridDim.x * 4) {
    const int* ip = idx0 + ((size_t)b * N + n) * 16;
    float bx = wg0 * xb[n] + wg1 * xb[N + n] + wg2 * xb[2 * N + n];
#pragma unroll
    for (int k = 0; k < 16; ++k) {
      int m = ip[k];
      float y = G1[((size_t)b * N + m) * 64 + lane] - bx;
      sum += y; sq += y * y;
    }
  }
#pragma unroll
  for (int off = 1; off < 16; off <<= 1) {
    sum += __shfl_xor(sum, off, 64);
    sq += __shfl_xor(sq, off, 64);
  }
  int g = lane >> 4;
  if ((lane & 15) == 0) { red[wav][g][0] = sum; red[wav][g][1] = sq; }
  __syncthreads();
  if (threadIdx.x < 8) {
    int gg = threadIdx.x >> 1, s = threadIdx.x & 1;
    float v = red[0][gg][s] + red[1][gg][s] + red[2][gg][s] + red[3][gg][s];
    atomicAdd(&stats1[(b * 4 + gg) * 2 + s], v);
  }
}

__global__ void gn_finalize_kernel(const float* __restrict__ raw, float* __restrict__ mi, float cnt)
{
  int i = threadIdx.x;
  if (i < 8) {
    float s = raw[i * 2], q = raw[i * 2 + 1];
    float m = s / cnt;
    float v = q / cnt - m * m;
    mi[i * 2] = m;
    mi[i * 2 + 1] = rsqrtf(v + 1e-5f);
  }
}

// ------------------------------------------------------------- flow conv2 ----
__launch_bounds__(256, 2)
__global__ void conv2_kernel(const float* __restrict__ G1, const float* __restrict__ xyz0,
    const float* __restrict__ fw1, const int* __restrict__ idx0,
    const float* __restrict__ fw2, const float* __restrict__ fb2,
    const float* __restrict__ fg1, const float* __restrict__ fbe1,
    const float* __restrict__ mi1, float* __restrict__ y2max, float* __restrict__ y2min,
    float* __restrict__ stats2, int N)
{
  __shared__ __align__(16) float x2[4][16][64];
  __shared__ float red[4][4][2];
  const int b = blockIdx.y;
  const int lane = threadIdx.x & 63;
  const int wav = rfl(threadIdx.x >> 6);
  float4 w[16];
#pragma unroll
  for (int i = 0; i < 16; ++i) w[i] = *(const float4*)&fw2[lane * 64 + i * 4];
  float wg0 = fw1[lane * 6 + 3], wg1 = fw1[lane * 6 + 4], wg2 = fw1[lane * 6 + 5];
  const int g = lane >> 4;
  float mu1 = mi1[(b * 4 + g) * 2], inv1 = mi1[(b * 4 + g) * 2 + 1];
  float sc1 = fg1[lane] * inv1;
  float sh1 = fbe1[lane] - mu1 * sc1;
  float fb2l = fb2[lane];
  const float* xb = xyz0 + (size_t)b * 3 * N;
  float sum = 0.f, sq = 0.f;
  for (int n = blockIdx.x * 4 + wav; n < N; n += gridDim.x * 4) {
    const int* ip = idx0 + ((size_t)b * N + n) * 16;
    float bx = wg0 * xb[n] + wg1 * xb[N + n] + wg2 * xb[2 * N + n];
#pragma unroll
    for (int k = 0; k < 16; ++k) {
      int m = ip[k];
      float y = G1[((size_t)b * N + m) * 64 + lane] - bx;
      x2[wav][k][lane] = leaky(y * sc1 + sh1);
    }
    float acc[16];
#pragma unroll
    for (int k = 0; k < 16; ++k) acc[k] = fb2l;
#pragma unroll
    for (int c4 = 0; c4 < 16; ++c4) {   // FULL unroll: w[c4] stays in VGPRs
      float4 w4 = w[c4];
#pragma unroll
      for (int k = 0; k < 16; ++k) {
        float4 x4 = *(const float4*)&x2[wav][k][c4 * 4];
        acc[k] = fmaf(w4.x, x4.x, acc[k]);
        acc[k] = fmaf(w4.y, x4.y, acc[k]);
        acc[k] = fmaf(w4.z, x4.z, acc[k]);
        acc[k] = fmaf(w4.w, x4.w, acc[k]);
      }
    }
    float mx = -3.0e38f, mn = 3.0e38f;
#pragma unroll
    for (int k = 0; k < 16; ++k) {
      mx = fmaxf(mx, acc[k]); mn = fminf(mn, acc[k]);
      sum += acc[k]; sq += acc[k] * acc[k];
    }
    y2max[((size_t)b * N + n) * 64 + lane] = mx;
    y2min[((size_t)b * N + n) * 64 + lane] = mn;
  }
#pragma unroll
  for (int off = 1; off < 16; off <<= 1) {
    sum += __shfl_xor(sum, off, 64);
    sq += __shfl_xor(sq, off, 64);
  }
  if ((lane & 15) == 0) { red[wav][g][0] = sum; red[wav][g][1] = sq; }
  __syncthreads();
  if (threadIdx.x < 8) {
    int gg = threadIdx.x >> 1, s = threadIdx.x & 1;
    float v = red[0][gg][s] + red[1][gg][s] + red[2][gg][s] + red[3][gg][s];
    atomicAdd(&stats2[(b * 4 + gg) * 2 + s], v);
  }
}

__launch_bounds__(256)
__global__ void flow_feat_kernel(const float* __restrict__ y2max, const float* __restrict__ y2min,
    const float* __restrict__ mi2, const float* __restrict__ fg2, const float* __restrict__ fbe2,
    float* __restrict__ ff, int N)
{
  size_t i = (size_t)blockIdx.x * blockDim.x + threadIdx.x;
  if (i >= (size_t)B_SZ * N * 64) return;
  int c = i & 63;
  size_t pn = i >> 6;
  int b = (int)(pn / N);
  int g = c >> 4;
  float mu = mi2[(b * 4 + g) * 2], inv = mi2[(b * 4 + g) * 2 + 1];
  float sc = fg2[c] * inv;
  float sh = fbe2[c] - mu * sc;
  float y = (sc >= 0.0f) ? y2max[i] : y2min[i];
  ff[i] = leaky(y * sc + sh);
}

// ------------------------------------------------------------------ gates ----
__launch_bounds__(256)
__global__ void gate_zr_kernel(const float* __restrict__ Sz, const float* __restrict__ Sr,
    const float* __restrict__ wz, const float* __restrict__ wr,
    const float* __restrict__ xyz0, const float* __restrict__ state,
    const int* __restrict__ idx0,
    float* __restrict__ zo, float* __restrict__ rs, int N)
{
  int b = blockIdx.y;
  int lane = threadIdx.x & 63, wav = rfl(threadIdx.x >> 6);
  float wz0 = wz[lane * 195 + 192], wz1 = wz[lane * 195 + 193], wz2 = wz[lane * 195 + 194];
  float wr0 = wr[lane * 195 + 192], wr1 = wr[lane * 195 + 193], wr2 = wr[lane * 195 + 194];
  const float* xb = xyz0 + (size_t)b * 3 * N;
  for (int n = blockIdx.x * 4 + wav; n < N; n += gridDim.x * 4) {
    const int* ip = idx0 + ((size_t)b * N + n) * 16;
    float u0 = xb[n], u1 = xb[N + n], u2 = xb[2 * N + n];
    float xz = wz0 * u0 + wz1 * u1 + wz2 * u2;
    float xr = wr0 * u0 + wr1 * u1 + wr2 * u2;
    float mz = -3.0e38f, mr = -3.0e38f;
#pragma unroll
    for (int k = 0; k < 16; ++k) {
      size_t mo = ((size_t)b * N + ip[k]) * 64 + lane;
      mz = fmaxf(mz, Sz[mo]);
      mr = fmaxf(mr, Sr[mo]);
    }
    size_t no = ((size_t)b * N + n) * 64 + lane;
    float z = 1.f / (1.f + expf(-(mz - xz)));
    float r = 1.f / (1.f + expf(-(mr - xr)));
    zo[no] = z;
    rs[no] = r * state[((size_t)b * 64 + lane) * N + n];
  }
}

__launch_bounds__(256)
__global__ void gate_q_ns_kernel(const float* __restrict__ Sq, const float* __restrict__ wq,
    const float* __restrict__ xyz0, const float* __restrict__ zo,
    const float* __restrict__ state, const int* __restrict__ idx0,
    float* __restrict__ ns, int N)
{
  int b = blockIdx.y;
  int lane = threadIdx.x & 63, wav = rfl(threadIdx.x >> 6);
  float wq0 = wq[lane * 195 + 192], wq1 = wq[lane * 195 + 193], wq2 = wq[lane * 195 + 194];
  const float* xb = xyz0 + (size_t)b * 3 * N;
  for (int n = blockIdx.x * 4 + wav; n < N; n += gridDim.x * 4) {
    const int* ip = idx0 + ((size_t)b * N + n) * 16;
    float xq = wq0 * xb[n] + wq1 * xb[N + n] + wq2 * xb[2 * N + n];
    float mq = -3.0e38f;
#pragma unroll
    for (int k = 0; k < 16; ++k)
      mq = fmaxf(mq, Sq[((size_t)b * N + ip[k]) * 64 + lane]);
    size_t no = ((size_t)b * N + n) * 64 + lane;
    float q = tanhf(mq - xq);
    float z = zo[no];
    float st = state[((size_t)b * 64 + lane) * N + n];
    ns[no] = (1.f - z) * st + z * q;
  }
}

// ------------------------------------------------------------------ align ----
__launch_bounds__(256, 2)
__global__ void align_kernel(const float* __restrict__ U, const float* __restrict__ V,
    const float* __restrict__ wa2, const float* __restrict__ ba2,
    const float* __restrict__ ns, const int* __restrict__ idx1,
    float* __restrict__ out, int N)
{
  __shared__ __align__(16) float xk[4][16][128];
  const int b = blockIdx.y;
  const int lane = threadIdx.x & 63;
  const int wav = rfl(threadIdx.x >> 6);
  float4 w[32];
#pragma unroll
  for (int i = 0; i < 32; ++i) w[i] = *(const float4*)&wa2[lane * 128 + i * 4];
  float ba = ba2[lane];
  const int n = blockIdx.x * 4 + wav;
  const int* ip = idx1 + ((size_t)b * N + n) * 16;
  int mk[16];
#pragma unroll
  for (int k = 0; k < 16; ++k) mk[k] = ip[k];
  const float* Vp = V + ((size_t)b * N + n) * 128;
  float v0 = Vp[lane], v1 = Vp[64 + lane];
#pragma unroll
  for (int k = 0; k < 16; ++k) {
    const float* Up = U + ((size_t)b * N + mk[k]) * 128;
    xk[wav][k][lane] = leaky(Up[lane] + v0);
    xk[wav][k][64 + lane] = leaky(Up[64 + lane] + v1);
  }
  float acc[16];
#pragma unroll
  for (int k = 0; k < 16; ++k) acc[k] = ba;
#pragma unroll
  for (int c4 = 0; c4 < 32; ++c4) {   // FULL unroll: w[c4] stays in VGPRs
    float4 w4 = w[c4];
#pragma unroll
    for (int k = 0; k < 16; ++k) {
      float4 x4 = *(const float4*)&xk[wav][k][c4 * 4];
      acc[k] = fmaf(w4.x, x4.x, acc[k]);
      acc[k] = fmaf(w4.y, x4.y, acc[k]);
      acc[k] = fmaf(w4.z, x4.z, acc[k]);
      acc[k] = fmaf(w4.w, x4.w, acc[k]);
    }
  }
  float m = acc[0];
#pragma unroll
  for (int k = 1; k < 16; ++k) m = fmaxf(m, acc[k]);
  float s = 0.f;
#pragma unroll
  for (int k = 0; k < 16; ++k) { acc[k] = expf(acc[k] - m); s += acc[k]; }
  float rinv = 1.0f / s;
  float o = 0.f;
#pragma unroll
  for (int k = 0; k < 16; ++k)
    o += acc[k] * rinv * ns[((size_t)b * N + mk[k]) * 64 + lane];
  out[((size_t)b * 64 + lane) * N + n] = o;
}

// ------------------------------------------------------------------ launch ----
extern "C" void kernel_launch(void* const* d_in, const int* in_sizes, int n_in,
                              void* d_out, int out_size, void* d_ws, size_t ws_size,
                              hipStream_t stream) {
  (void)n_in; (void)out_size; (void)ws_size;
  const float* xyz0 = (const float*)d_in[0];
  const float* xyz1 = (const float*)d_in[1];
  const float* state = (const float*)d_in[2];
  const float* corr0 = (const float*)d_in[3];
  const float* feat0 = (const float*)d_in[4];
  const float* feat1 = (const float*)d_in[5];
  const float* flow0 = (const float*)d_in[6];
  const float* fw1 = (const float*)d_in[7];
  const float* fb1 = (const float*)d_in[8];
  const float* fg1 = (const float*)d_in[9];
  const float* fbe1 = (const float*)d_in[10];
  const float* fw2 = (const float*)d_in[11];
  const float* fb2 = (const float*)d_in[12];
  const float* fg2 = (const float*)d_in[13];
  const float* fbe2 = (const float*)d_in[14];
  const float* wz = (const float*)d_in[15];
  const float* bz = (const float*)d_in[16];
  const float* wr = (const float*)d_in[17];
  const float* br = (const float*)d_in[18];
  const float* wq = (const float*)d_in[19];
  const float* bq = (const float*)d_in[20];
  const float* wa1 = (const float*)d_in[21];
  const float* ba1 = (const float*)d_in[22];
  const float* wa2 = (const float*)d_in[23];
  const float* ba2 = (const float*)d_in[24];
  float* out = (float*)d_out;

  const int N = in_sizes[0] / (3 * B_SZ);  // 4096
  char* wsb = (char*)d_ws;
  size_t off = 0;
  auto take = [&](size_t bytes) -> char* {
    char* p = wsb + off;
    off += (bytes + 255) & ~(size_t)255;
    return p;
  };
  const size_t PN = (size_t)B_SZ * N;
  float* U    = (float*)take(PN * 128 * 4);
  float* V    = (float*)take(PN * 128 * 4);
  float4* pk0 = (float4*)take(PN * 4 * 4);
  int*   idx0 = (int*)  take(PN * 16 * 4);
  int*   idx1 = (int*)  take(PN * 16 * 4);
  float* G1   = (float*)take(PN * 64 * 4);
  float* y2mx = (float*)take(PN * 64 * 4);
  float* y2mn = (float*)take(PN * 64 * 4);
  float* ff   = (float*)take(PN * 64 * 4);
  float* Sz   = (float*)take(PN * 64 * 4);
  float* Sr   = (float*)take(PN * 64 * 4);
  float* Sq   = (float*)take(PN * 64 * 4);
  float* zg   = (float*)take(PN * 64 * 4);
  float* rs   = (float*)take(PN * 64 * 4);
  float* ns   = (float*)take(PN * 64 * 4);
  float* stats = (float*)take(256);
  float* raw1 = stats, *raw2 = stats + 16, *mi1 = stats + 32, *mi2 = stats + 48;

  const float* FN = nullptr;
  const float cntv = 16.0f * N * 16.0f;

  hipMemsetAsync(raw1, 0, 32 * sizeof(float), stream);

  pack_kernel<<<dim3((N + 255) / 256, B_SZ), 256, 0, stream>>>(xyz0, pk0, N);
  knn_wave_kernel<<<dim3(N / 4, B_SZ), 256, 0, stream>>>(pk0, xyz0, idx0, N);
  knn_wave_kernel<<<dim3(N / 4, B_SZ), 256, 0, stream>>>(pk0, xyz1, idx1, N);

  // G1 = fw1[:,:3]@flow0 + fw1[:,3:]@xyz0 + fb1
  proj_kernel<7><<<dim3(N / 16, B_SZ, 1), 256, 0, stream>>>(
      fw1, fw1, fb1, fb1, G1, G1, 0, 0, 64, 6, N,
      flow0, 3, 0, N, 1, 1.f,  xyz0, 3, 3, N, 1, 1.f,
      FN, 0, 0, 1, 1, 0.f,     FN, 0, 0, 1, 1, 0.f);

  gn1_stats_kernel<<<dim3(256, B_SZ), 256, 0, stream>>>(G1, xyz0, fw1, idx0, raw1, N);
  gn_finalize_kernel<<<1, 64, 0, stream>>>(raw1, mi1, cntv);
  conv2_kernel<<<dim3(512, B_SZ), 256, 0, stream>>>(G1, xyz0, fw1, idx0, fw2, fb2, fg1, fbe1,
      mi1, y2mx, y2mn, raw2, N);
  gn_finalize_kernel<<<1, 64, 0, stream>>>(raw2, mi2, cntv);
  flow_feat_kernel<<<dim3((unsigned)(PN * 64 / 256)), 256, 0, stream>>>(y2mx, y2mn, mi2, fg2, fbe2, ff, N);

  // Sz/Sr in one launch (z selects weights)
  proj_kernel<195><<<dim3(N / 16, B_SZ, 2), 256, 0, stream>>>(
      wz, wr, bz, br, Sz, Sr, 0, 0, 64, 195, N,
      corr0, 64, 0, N, 1, 1.f,   ff, 64, 64, 1, 64, 1.f,
      state, 64, 128, N, 1, 1.f, xyz0, 3, 192, N, 1, 1.f);

  gate_zr_kernel<<<dim3(256, B_SZ), 256, 0, stream>>>(Sz, Sr, wz, wr, xyz0, state, idx0, zg, rs, N);

  proj_kernel<195><<<dim3(N / 16, B_SZ, 1), 256, 0, stream>>>(
      wq, wq, bq, bq, Sq, Sq, 0, 0, 64, 195, N,
      corr0, 64, 0, N, 1, 1.f,   ff, 64, 64, 1, 64, 1.f,
      rs, 64, 128, 1, 64, 1.f,   xyz0, 3, 192, N, 1, 1.f);

  gate_q_ns_kernel<<<dim3(256, B_SZ), 256, 0, stream>>>(Sq, wq, xyz0, zg, state, idx0, ns, N);

  // U = wa1[:, :128]@feat0 + wa1[:,256:]@xyz0  (two 64-row slices via z)
  proj_kernel<131><<<dim3(N / 16, B_SZ, 2), 256, 0, stream>>>(
      wa1, wa1 + (size_t)64 * 259, FN, FN, U, U, 0, 64, 128, 259, N,
      feat0, 128, 0, N, 1, 1.f,  xyz0, 3, 256, N, 1, 1.f,
      FN, 0, 0, 1, 1, 0.f,       FN, 0, 0, 1, 1, 0.f);
  // V = wa1[:,128:256]@feat1 - wa1[:,256:]@xyz1 + ba1
  proj_kernel<131><<<dim3(N / 16, B_SZ, 2), 256, 0, stream>>>(
      wa1, wa1 + (size_t)64 * 259, ba1, ba1, V, V, 0, 64, 128, 259, N,
      feat1, 128, 128, N, 1, 1.f, xyz1, 3, 256, N, 1, -1.f,
      FN, 0, 0, 1, 1, 0.f,        FN, 0, 0, 1, 1, 0.f);

  align_kernel<<<dim3(N / 4, B_SZ), 256, 0, stream>>>(U, V, wa2, ba2, ns, idx1, out, N);
}

// Round 5
// 408.126 us; speedup vs baseline: 1.4870x; 1.2726x over previous
//
#include <hip/hip_runtime.h>

#define B_SZ 2

__device__ __forceinline__ int rfl(int x) { return __builtin_amdgcn_readfirstlane(x); }
__device__ __forceinline__ float leaky(float v) { return v >= 0.f ? v : 0.1f * v; }

// ---------------------------------------------------------------- KNN ----
__launch_bounds__(256)
__global__ void pack_kernel(const float* __restrict__ xyz, float4* __restrict__ out, int N)
{
  int b = blockIdx.y;
  int i = blockIdx.x * 256 + threadIdx.x;
  if (i >= N) return;
  const float* p = xyz + (size_t)b * 3 * N;
  float x = p[i], y = p[N + i], z = p[2 * N + i];
  out[(size_t)b * N + i] = make_float4(x, y, z, x * x + y * y + z * z);
}

// One wave per query. Top-16 kept lane-distributed (lanes 0..15, ascending).
__launch_bounds__(256)
__global__ void knn_wave_kernel(const float4* __restrict__ pk, const float* __restrict__ q,
                                int* __restrict__ idx, int N)
{
  __shared__ float sx[1024], sy[1024], sz[1024], sw[1024];
  int b = blockIdx.y;
  int lane = threadIdx.x & 63, wav = rfl(threadIdx.x >> 6);
  int qi = blockIdx.x * 4 + wav;
  const float* qb = q + (size_t)b * 3 * N;
  float qx = qb[qi], qy = qb[N + qi], qz = qb[2 * N + qi];
  float qq = qx * qx + qy * qy + qz * qz;
  float bd = 3.0e38f;
  int   bi = 0;
  float thr = 3.0e38f;
  const float4* pb = pk + (size_t)b * N;
  for (int ch = 0; ch < N; ch += 1024) {
    __syncthreads();
    for (int i = threadIdx.x; i < 1024; i += 256) {
      float4 v = pb[ch + i];
      sx[i] = v.x; sy[i] = v.y; sz[i] = v.z; sw[i] = v.w;
    }
    __syncthreads();
    for (int sub = 0; sub < 1024; sub += 64) {
      int c = sub + lane;
      float dl = (qq + sw[c]) - 2.0f * (qx * sx[c] + qy * sy[c] + qz * sz[c]);
      unsigned long long qm = __ballot(dl < thr);
      while (qm) {
        int l = __ffsll(qm) - 1;
        qm &= qm - 1;
        float dc = __shfl(dl, l);
        unsigned long long rm = __ballot(lane < 16 && bd <= dc);
        int pos = __popcll(rm);
        if (pos < 16) {
          int ic = ch + sub + l;
          float pbd = __shfl(bd, lane - 1);
          int   pbi = __shfl(bi, lane - 1);
          if (lane < 16) {
            if (lane == pos)      { bd = dc;  bi = ic; }
            else if (lane > pos)  { bd = pbd; bi = pbi; }
          }
          thr = __shfl(bd, 15);
        }
      }
    }
  }
  if (lane < 16) idx[((size_t)b * N + qi) * 16 + lane] = bi;
}

// -------------------------------------------------- weight pre-transpose ----
// Writes Wt[k][o] compacted/transposed weight panels + concat biases.
__launch_bounds__(256)
__global__ void prep_w_kernel(const float* __restrict__ wz, const float* __restrict__ wr,
    const float* __restrict__ wq, const float* __restrict__ wa1,
    const float* __restrict__ bz, const float* __restrict__ br,
    float* __restrict__ WtZR, float* __restrict__ WtQ,
    float* __restrict__ WtU, float* __restrict__ WtV, float* __restrict__ bZR)
{
  int job = blockIdx.x;
  int tid = threadIdx.x;
  if (job == 0) {                      // WtZR [195][128]: o<64 -> wz row, else wr
    for (int e = tid; e < 195 * 128; e += 256) {
      int k = e >> 7, o = e & 127;
      const float* w = (o < 64) ? wz : wr;
      WtZR[(size_t)k * 128 + o] = w[(size_t)(o & 63) * 195 + k];
    }
    if (tid < 128) bZR[tid] = (tid < 64) ? bz[tid] : br[tid - 64];
  } else if (job == 1) {               // WtQ [195][64]
    for (int e = tid; e < 195 * 64; e += 256) {
      int k = e >> 6, o = e & 63;
      WtQ[(size_t)k * 64 + o] = wq[(size_t)o * 195 + k];
    }
  } else if (job == 2) {               // WtU [131][128]: cols 0..127 then 256..258
    for (int e = tid; e < 131 * 128; e += 256) {
      int k = e >> 7, o = e & 127;
      int col = (k < 128) ? k : 256 + (k - 128);
      WtU[(size_t)k * 128 + o] = wa1[(size_t)o * 259 + col];
    }
  } else {                             // WtV [131][128]: cols 128..255 then -(256..258)
    for (int e = tid; e < 131 * 128; e += 256) {
      int k = e >> 7, o = e & 127;
      float v = (k < 128) ? wa1[(size_t)o * 259 + 128 + k]
                          : -wa1[(size_t)o * 259 + 256 + (k - 128)];
      WtV[(size_t)k * 128 + o] = v;
    }
  }
}

// -------------------------------------------------- tiled projection GEMM ----
// out[n'][oo+o] = bias[oo+o] + sum_k X[k][n'] * Wt[k][oo+o]
// X assembled from up to 4 segments; layout l: 0 = [B][C][N], 1 = [C][B*N].
#define KC 66
__launch_bounds__(256)
__global__ void projT_kernel(const float* __restrict__ Wt, int K, int WOUT,
    const float* __restrict__ bias, float* __restrict__ out,
    int N, int PN,
    const float* __restrict__ s0, int c0, int l0,
    const float* __restrict__ s1, int c1, int l1,
    const float* __restrict__ s2, int c2, int l2,
    const float* __restrict__ s3, int c3, int l3)
{
  __shared__ __align__(16) float Ws[KC][68];
  __shared__ __align__(16) float Xs[KC][68];
  const int n0 = blockIdx.x * 64;          // global point index base
  const int oo = blockIdx.y * 64;          // output-channel tile base
  const int b = n0 / N;
  const int nn0 = n0 - b * N;
  const int tid = threadIdx.x;
  const int tx = tid & 15, ty = tid >> 4;
  const int o4 = tx * 4, n4 = ty * 4;
  float acc[4][4];
#pragma unroll
  for (int i = 0; i < 4; ++i)
#pragma unroll
    for (int j = 0; j < 4; ++j)
      acc[i][j] = bias ? bias[oo + o4 + j] : 0.0f;

  const int e01 = c0 + c1, e012 = c0 + c1 + c2;
  for (int k0 = 0; k0 < K; k0 += KC) {
    const int kc = min(KC, K - k0);
    __syncthreads();
    for (int e = tid; e < kc * 64; e += 256) {
      int k = e >> 6, o = e & 63;
      Ws[k][o] = Wt[(size_t)(k0 + k) * WOUT + oo + o];
    }
    for (int e = tid; e < kc * 64; e += 256) {
      int k = e >> 6, j = e & 63;
      int c = k0 + k;                      // wave-uniform
      float v;
      if (c < c0)        v = l0 ? s0[(size_t)c * PN + n0 + j]
                                : s0[((size_t)b * c0 + c) * N + nn0 + j];
      else if (c < e01)  { int cc = c - c0;
                           v = l1 ? s1[(size_t)cc * PN + n0 + j]
                                  : s1[((size_t)b * c1 + cc) * N + nn0 + j]; }
      else if (c < e012) { int cc = c - e01;
                           v = l2 ? s2[(size_t)cc * PN + n0 + j]
                                  : s2[((size_t)b * c2 + cc) * N + nn0 + j]; }
      else               { int cc = c - e012;
                           v = l3 ? s3[(size_t)cc * PN + n0 + j]
                                  : s3[((size_t)b * c3 + cc) * N + nn0 + j]; }
      Xs[k][j] = v;
    }
    __syncthreads();
#pragma unroll 2
    for (int k = 0; k < kc; ++k) {
      float4 wv = *(const float4*)&Ws[k][o4];
      float4 xv = *(const float4*)&Xs[k][n4];
      acc[0][0] = fmaf(xv.x, wv.x, acc[0][0]); acc[0][1] = fmaf(xv.x, wv.y, acc[0][1]);
      acc[0][2] = fmaf(xv.x, wv.z, acc[0][2]); acc[0][3] = fmaf(xv.x, wv.w, acc[0][3]);
      acc[1][0] = fmaf(xv.y, wv.x, acc[1][0]); acc[1][1] = fmaf(xv.y, wv.y, acc[1][1]);
      acc[1][2] = fmaf(xv.y, wv.z, acc[1][2]); acc[1][3] = fmaf(xv.y, wv.w, acc[1][3]);
      acc[2][0] = fmaf(xv.z, wv.x, acc[2][0]); acc[2][1] = fmaf(xv.z, wv.y, acc[2][1]);
      acc[2][2] = fmaf(xv.z, wv.z, acc[2][2]); acc[2][3] = fmaf(xv.z, wv.w, acc[2][3]);
      acc[3][0] = fmaf(xv.w, wv.x, acc[3][0]); acc[3][1] = fmaf(xv.w, wv.y, acc[3][1]);
      acc[3][2] = fmaf(xv.w, wv.z, acc[3][2]); acc[3][3] = fmaf(xv.w, wv.w, acc[3][3]);
    }
  }
#pragma unroll
  for (int i = 0; i < 4; ++i) {
    float4 r = make_float4(acc[i][0], acc[i][1], acc[i][2], acc[i][3]);
    *(float4*)&out[(size_t)(n0 + n4 + i) * WOUT + oo + o4] = r;
  }
}

// --------------------------------------------------------- small proj (G1) ----
__device__ __forceinline__ void seg_accumL(const float* __restrict__ p, int cnt,
    const float* __restrict__ WL, int sC, int sN, long n0, float acc[4])
{
#pragma unroll 4
  for (int c = 0; c < cnt; ++c) {
    float w = WL[c];
    const float* pp = p + (size_t)c * sC + (size_t)n0 * sN;
#pragma unroll
    for (int m = 0; m < 4; ++m)
      acc[m] = fmaf(w, pp[(size_t)m * sN], acc[m]);
  }
}

template<int WP>
__launch_bounds__(256)
__global__ void proj_kernel(
    const float* __restrict__ W0, const float* __restrict__ bias,
    float* __restrict__ out, int OUTS, int wld, int N,
    const float* __restrict__ s0, int c0, int w0,
    const float* __restrict__ s1, int c1, int w1)
{
  __shared__ float Wl[64 * WP];
  const int b = blockIdx.y;
  const int lane = threadIdx.x & 63;
  const int wav = rfl(threadIdx.x >> 6);
  int lco = 0;
  for (int r = wav; r < 64; r += 4)
    for (int c = lane; c < c0; c += 64)
      Wl[r * WP + c] = W0[(size_t)r * wld + w0 + c];
  lco = c0;
  for (int r = wav; r < 64; r += 4)
    for (int c = lane; c < c1; c += 64)
      Wl[r * WP + lco + c] = W0[(size_t)r * wld + w1 + c];
  __syncthreads();
  const long n0 = ((long)blockIdx.x * 4 + wav) * 4;
  float bv = bias ? bias[lane] : 0.0f;
  float acc[4] = {bv, bv, bv, bv};
  const float* WL = &Wl[lane * WP];
  seg_accumL(s0 + (size_t)b * c0 * N, c0, WL, N, 1, n0, acc);
  seg_accumL(s1 + (size_t)b * c1 * N, c1, WL + c0, N, 1, n0, acc);
#pragma unroll
  for (int m = 0; m < 4; ++m)
    out[((size_t)b * N + n0 + m) * OUTS + lane] = acc[m];
}

// ------------------------------------------------------------- groupnorm ----
__launch_bounds__(256)
__global__ void gn1_stats_kernel(const float* __restrict__ G1, const float* __restrict__ xyz0,
    const float* __restrict__ fw1, const int* __restrict__ idx0,
    float* __restrict__ stats1, int N)
{
  __shared__ float red[4][4][2];
  int b = blockIdx.y;
  int lane = threadIdx.x & 63, wav = rfl(threadIdx.x >> 6);
  float wg0 = fw1[lane * 6 + 3], wg1 = fw1[lane * 6 + 4], wg2 = fw1[lane * 6 + 5];
  const float* xb = xyz0 + (size_t)b * 3 * N;
  float sum = 0.f, sq = 0.f;
  for (int n = blockIdx.x * 4 + wav; n < N; n += gridDim.x * 4) {
    const int* ip = idx0 + ((size_t)b * N + n) * 16;
    float bx = wg0 * xb[n] + wg1 * xb[N + n] + wg2 * xb[2 * N + n];
#pragma unroll
    for (int k = 0; k < 16; ++k) {
      int m = ip[k];
      float y = G1[((size_t)b * N + m) * 64 + lane] - bx;
      sum += y; sq += y * y;
    }
  }
#pragma unroll
  for (int off = 1; off < 16; off <<= 1) {
    sum += __shfl_xor(sum, off, 64);
    sq += __shfl_xor(sq, off, 64);
  }
  int g = lane >> 4;
  if ((lane & 15) == 0) { red[wav][g][0] = sum; red[wav][g][1] = sq; }
  __syncthreads();
  if (threadIdx.x < 8) {
    int gg = threadIdx.x >> 1, s = threadIdx.x & 1;
    float v = red[0][gg][s] + red[1][gg][s] + red[2][gg][s] + red[3][gg][s];
    atomicAdd(&stats1[(b * 4 + gg) * 2 + s], v);
  }
}

__global__ void gn_finalize_kernel(const float* __restrict__ raw, float* __restrict__ mi, float cnt)
{
  int i = threadIdx.x;
  if (i < 8) {
    float s = raw[i * 2], q = raw[i * 2 + 1];
    float m = s / cnt;
    float v = q / cnt - m * m;
    mi[i * 2] = m;
    mi[i * 2 + 1] = rsqrtf(v + 1e-5f);
  }
}

// ------------------------------------------------------------- flow conv2 ----
__launch_bounds__(256, 2)
__global__ void conv2_kernel(const float* __restrict__ G1, const float* __restrict__ xyz0,
    const float* __restrict__ fw1, const int* __restrict__ idx0,
    const float* __restrict__ fw2, const float* __restrict__ fb2,
    const float* __restrict__ fg1, const float* __restrict__ fbe1,
    const float* __restrict__ mi1, float* __restrict__ y2max, float* __restrict__ y2min,
    float* __restrict__ stats2, int N)
{
  __shared__ __align__(16) float x2[4][16][64];
  __shared__ float red[4][4][2];
  const int b = blockIdx.y;
  const int lane = threadIdx.x & 63;
  const int wav = rfl(threadIdx.x >> 6);
  float4 w[16];
#pragma unroll
  for (int i = 0; i < 16; ++i) w[i] = *(const float4*)&fw2[lane * 64 + i * 4];
  float wg0 = fw1[lane * 6 + 3], wg1 = fw1[lane * 6 + 4], wg2 = fw1[lane * 6 + 5];
  const int g = lane >> 4;
  float mu1 = mi1[(b * 4 + g) * 2], inv1 = mi1[(b * 4 + g) * 2 + 1];
  float sc1 = fg1[lane] * inv1;
  float sh1 = fbe1[lane] - mu1 * sc1;
  float fb2l = fb2[lane];
  const float* xb = xyz0 + (size_t)b * 3 * N;
  float sum = 0.f, sq = 0.f;
  for (int n = blockIdx.x * 4 + wav; n < N; n += gridDim.x * 4) {
    const int* ip = idx0 + ((size_t)b * N + n) * 16;
    float bx = wg0 * xb[n] + wg1 * xb[N + n] + wg2 * xb[2 * N + n];
#pragma unroll
    for (int k = 0; k < 16; ++k) {
      int m = ip[k];
      float y = G1[((size_t)b * N + m) * 64 + lane] - bx;
      x2[wav][k][lane] = leaky(y * sc1 + sh1);
    }
    float acc[16];
#pragma unroll
    for (int k = 0; k < 16; ++k) acc[k] = fb2l;
#pragma unroll
    for (int c4 = 0; c4 < 16; ++c4) {
      float4 w4 = w[c4];
#pragma unroll
      for (int k = 0; k < 16; ++k) {
        float4 x4 = *(const float4*)&x2[wav][k][c4 * 4];
        acc[k] = fmaf(w4.x, x4.x, acc[k]);
        acc[k] = fmaf(w4.y, x4.y, acc[k]);
        acc[k] = fmaf(w4.z, x4.z, acc[k]);
        acc[k] = fmaf(w4.w, x4.w, acc[k]);
      }
    }
    float mx = -3.0e38f, mn = 3.0e38f;
#pragma unroll
    for (int k = 0; k < 16; ++k) {
      mx = fmaxf(mx, acc[k]); mn = fminf(mn, acc[k]);
      sum += acc[k]; sq += acc[k] * acc[k];
    }
    y2max[((size_t)b * N + n) * 64 + lane] = mx;
    y2min[((size_t)b * N + n) * 64 + lane] = mn;
  }
#pragma unroll
  for (int off = 1; off < 16; off <<= 1) {
    sum += __shfl_xor(sum, off, 64);
    sq += __shfl_xor(sq, off, 64);
  }
  if ((lane & 15) == 0) { red[wav][g][0] = sum; red[wav][g][1] = sq; }
  __syncthreads();
  if (threadIdx.x < 8) {
    int gg = threadIdx.x >> 1, s = threadIdx.x & 1;
    float v = red[0][gg][s] + red[1][gg][s] + red[2][gg][s] + red[3][gg][s];
    atomicAdd(&stats2[(b * 4 + gg) * 2 + s], v);
  }
}

// ff output now channel-major: ff_t[c][B*N]
__launch_bounds__(256)
__global__ void flow_feat_kernel(const float* __restrict__ y2max, const float* __restrict__ y2min,
    const float* __restrict__ mi2, const float* __restrict__ fg2, const float* __restrict__ fbe2,
    float* __restrict__ ff_t, int N, int PN)
{
  size_t i = (size_t)blockIdx.x * blockDim.x + threadIdx.x;
  if (i >= (size_t)B_SZ * N * 64) return;
  int c = i & 63;
  size_t pn = i >> 6;
  int b = (int)(pn / N);
  int g = c >> 4;
  float mu = mi2[(b * 4 + g) * 2], inv = mi2[(b * 4 + g) * 2 + 1];
  float sc = fg2[c] * inv;
  float sh = fbe2[c] - mu * sc;
  float y = (sc >= 0.0f) ? y2max[i] : y2min[i];
  ff_t[(size_t)c * PN + pn] = leaky(y * sc + sh);
}

// ------------------------------------------------------------------ gates ----
__launch_bounds__(256)
__global__ void gate_zr_kernel(const float* __restrict__ Szr,
    const float* __restrict__ wz, const float* __restrict__ wr,
    const float* __restrict__ xyz0, const float* __restrict__ state,
    const int* __restrict__ idx0,
    float* __restrict__ zo, float* __restrict__ rs_t, int N, int PN)
{
  int b = blockIdx.y;
  int lane = threadIdx.x & 63, wav = rfl(threadIdx.x >> 6);
  float wz0 = wz[lane * 195 + 192], wz1 = wz[lane * 195 + 193], wz2 = wz[lane * 195 + 194];
  float wr0 = wr[lane * 195 + 192], wr1 = wr[lane * 195 + 193], wr2 = wr[lane * 195 + 194];
  const float* xb = xyz0 + (size_t)b * 3 * N;
  for (int n = blockIdx.x * 4 + wav; n < N; n += gridDim.x * 4) {
    const int* ip = idx0 + ((size_t)b * N + n) * 16;
    float u0 = xb[n], u1 = xb[N + n], u2 = xb[2 * N + n];
    float xz = wz0 * u0 + wz1 * u1 + wz2 * u2;
    float xr = wr0 * u0 + wr1 * u1 + wr2 * u2;
    float mz = -3.0e38f, mr = -3.0e38f;
#pragma unroll
    for (int k = 0; k < 16; ++k) {
      size_t mo = ((size_t)b * N + ip[k]) * 128 + lane;
      mz = fmaxf(mz, Szr[mo]);
      mr = fmaxf(mr, Szr[mo + 64]);
    }
    size_t no = ((size_t)b * N + n) * 64 + lane;
    float z = 1.f / (1.f + expf(-(mz - xz)));
    float r = 1.f / (1.f + expf(-(mr - xr)));
    zo[no] = z;
    rs_t[(size_t)lane * PN + (size_t)b * N + n] = r * state[((size_t)b * 64 + lane) * N + n];
  }
}

__launch_bounds__(256)
__global__ void gate_q_ns_kernel(const float* __restrict__ Sq, const float* __restrict__ wq,
    const float* __restrict__ xyz0, const float* __restrict__ zo,
    const float* __restrict__ state, const int* __restrict__ idx0,
    float* __restrict__ ns, int N)
{
  int b = blockIdx.y;
  int lane = threadIdx.x & 63, wav = rfl(threadIdx.x >> 6);
  float wq0 = wq[lane * 195 + 192], wq1 = wq[lane * 195 + 193], wq2 = wq[lane * 195 + 194];
  const float* xb = xyz0 + (size_t)b * 3 * N;
  for (int n = blockIdx.x * 4 + wav; n < N; n += gridDim.x * 4) {
    const int* ip = idx0 + ((size_t)b * N + n) * 16;
    float xq = wq0 * xb[n] + wq1 * xb[N + n] + wq2 * xb[2 * N + n];
    float mq = -3.0e38f;
#pragma unroll
    for (int k = 0; k < 16; ++k)
      mq = fmaxf(mq, Sq[((size_t)b * N + ip[k]) * 64 + lane]);
    size_t no = ((size_t)b * N + n) * 64 + lane;
    float q = tanhf(mq - xq);
    float z = zo[no];
    float st = state[((size_t)b * 64 + lane) * N + n];
    ns[no] = (1.f - z) * st + z * q;
  }
}

// ------------------------------------------------------------------ align ----
__launch_bounds__(256, 2)
__global__ void align_kernel(const float* __restrict__ U, const float* __restrict__ V,
    const float* __restrict__ wa2, const float* __restrict__ ba2,
    const float* __restrict__ ns, const int* __restrict__ idx1,
    float* __restrict__ out, int N)
{
  __shared__ __align__(16) float xk[4][16][128];
  const int b = blockIdx.y;
  const int lane = threadIdx.x & 63;
  const int wav = rfl(threadIdx.x >> 6);
  float4 w[32];
#pragma unroll
  for (int i = 0; i < 32; ++i) w[i] = *(const float4*)&wa2[lane * 128 + i * 4];
  float ba = ba2[lane];
  const int n = blockIdx.x * 4 + wav;
  const int* ip = idx1 + ((size_t)b * N + n) * 16;
  int mk[16];
#pragma unroll
  for (int k = 0; k < 16; ++k) mk[k] = ip[k];
  const float* Vp = V + ((size_t)b * N + n) * 128;
  float v0 = Vp[lane], v1 = Vp[64 + lane];
#pragma unroll
  for (int k = 0; k < 16; ++k) {
    const float* Up = U + ((size_t)b * N + mk[k]) * 128;
    xk[wav][k][lane] = leaky(Up[lane] + v0);
    xk[wav][k][64 + lane] = leaky(Up[64 + lane] + v1);
  }
  float acc[16];
#pragma unroll
  for (int k = 0; k < 16; ++k) acc[k] = ba;
#pragma unroll
  for (int c4 = 0; c4 < 32; ++c4) {
    float4 w4 = w[c4];
#pragma unroll
    for (int k = 0; k < 16; ++k) {
      float4 x4 = *(const float4*)&xk[wav][k][c4 * 4];
      acc[k] = fmaf(w4.x, x4.x, acc[k]);
      acc[k] = fmaf(w4.y, x4.y, acc[k]);
      acc[k] = fmaf(w4.z, x4.z, acc[k]);
      acc[k] = fmaf(w4.w, x4.w, acc[k]);
    }
  }
  float m = acc[0];
#pragma unroll
  for (int k = 1; k < 16; ++k) m = fmaxf(m, acc[k]);
  float s = 0.f;
#pragma unroll
  for (int k = 0; k < 16; ++k) { acc[k] = expf(acc[k] - m); s += acc[k]; }
  float rinv = 1.0f / s;
  float o = 0.f;
#pragma unroll
  for (int k = 0; k < 16; ++k)
    o += acc[k] * rinv * ns[((size_t)b * N + mk[k]) * 64 + lane];
  out[((size_t)b * 64 + lane) * N + n] = o;
}

// ------------------------------------------------------------------ launch ----
extern "C" void kernel_launch(void* const* d_in, const int* in_sizes, int n_in,
                              void* d_out, int out_size, void* d_ws, size_t ws_size,
                              hipStream_t stream) {
  (void)n_in; (void)out_size; (void)ws_size;
  const float* xyz0 = (const float*)d_in[0];
  const float* xyz1 = (const float*)d_in[1];
  const float* state = (const float*)d_in[2];
  const float* corr0 = (const float*)d_in[3];
  const float* feat0 = (const float*)d_in[4];
  const float* feat1 = (const float*)d_in[5];
  const float* flow0 = (const float*)d_in[6];
  const float* fw1 = (const float*)d_in[7];
  const float* fb1 = (const float*)d_in[8];
  const float* fg1 = (const float*)d_in[9];
  const float* fbe1 = (const float*)d_in[10];
  const float* fw2 = (const float*)d_in[11];
  const float* fb2 = (const float*)d_in[12];
  const float* fg2 = (const float*)d_in[13];
  const float* fbe2 = (const float*)d_in[14];
  const float* wz = (const float*)d_in[15];
  const float* bz = (const float*)d_in[16];
  const float* wr = (const float*)d_in[17];
  const float* br = (const float*)d_in[18];
  const float* wq = (const float*)d_in[19];
  const float* bq = (const float*)d_in[20];
  const float* wa1 = (const float*)d_in[21];
  const float* ba1 = (const float*)d_in[22];
  const float* wa2 = (const float*)d_in[23];
  const float* ba2 = (const float*)d_in[24];
  float* out = (float*)d_out;

  const int N = in_sizes[0] / (3 * B_SZ);  // 4096
  const int PN = B_SZ * N;                 // 8192
  char* wsb = (char*)d_ws;
  size_t off = 0;
  auto take = [&](size_t bytes) -> char* {
    char* p = wsb + off;
    off += (bytes + 255) & ~(size_t)255;
    return p;
  };
  float* U    = (float*)take((size_t)PN * 128 * 4);
  float* V    = (float*)take((size_t)PN * 128 * 4);
  float* Szr  = (float*)take((size_t)PN * 128 * 4);
  float4* pk0 = (float4*)take((size_t)PN * 4 * 4);
  int*   idx0 = (int*)  take((size_t)PN * 16 * 4);
  int*   idx1 = (int*)  take((size_t)PN * 16 * 4);
  float* G1   = (float*)take((size_t)PN * 64 * 4);
  float* y2mx = (float*)take((size_t)PN * 64 * 4);
  float* y2mn = (float*)take((size_t)PN * 64 * 4);
  float* ff_t = (float*)take((size_t)PN * 64 * 4);
  float* Sq   = (float*)take((size_t)PN * 64 * 4);
  float* zg   = (float*)take((size_t)PN * 64 * 4);
  float* rs_t = (float*)take((size_t)PN * 64 * 4);
  float* ns   = (float*)take((size_t)PN * 64 * 4);
  float* WtZR = (float*)take(195 * 128 * 4);
  float* WtQ  = (float*)take(195 * 64 * 4);
  float* WtU  = (float*)take(131 * 128 * 4);
  float* WtV  = (float*)take(131 * 128 * 4);
  float* bZR  = (float*)take(128 * 4);
  float* stats = (float*)take(256);
  float* raw1 = stats, *raw2 = stats + 16, *mi1 = stats + 32, *mi2 = stats + 48;

  const float* FN = nullptr;
  const float cntv = 16.0f * N * 16.0f;

  hipMemsetAsync(raw1, 0, 32 * sizeof(float), stream);

  pack_kernel<<<dim3((N + 255) / 256, B_SZ), 256, 0, stream>>>(xyz0, pk0, N);
  prep_w_kernel<<<4, 256, 0, stream>>>(wz, wr, wq, wa1, bz, br, WtZR, WtQ, WtU, WtV, bZR);
  knn_wave_kernel<<<dim3(N / 4, B_SZ), 256, 0, stream>>>(pk0, xyz0, idx0, N);
  knn_wave_kernel<<<dim3(N / 4, B_SZ), 256, 0, stream>>>(pk0, xyz1, idx1, N);

  // G1 = fw1[:,:3]@flow0 + fw1[:,3:]@xyz0 + fb1   (tiny K=6, old path)
  proj_kernel<7><<<dim3(N / 16, B_SZ), 256, 0, stream>>>(
      fw1, fb1, G1, 64, 6, N, flow0, 3, 0, xyz0, 3, 3);

  gn1_stats_kernel<<<dim3(256, B_SZ), 256, 0, stream>>>(G1, xyz0, fw1, idx0, raw1, N);
  gn_finalize_kernel<<<1, 64, 0, stream>>>(raw1, mi1, cntv);
  conv2_kernel<<<dim3(512, B_SZ), 256, 0, stream>>>(G1, xyz0, fw1, idx0, fw2, fb2, fg1, fbe1,
      mi1, y2mx, y2mn, raw2, N);
  gn_finalize_kernel<<<1, 64, 0, stream>>>(raw2, mi2, cntv);
  flow_feat_kernel<<<dim3((unsigned)((size_t)PN * 64 / 256)), 256, 0, stream>>>(
      y2mx, y2mn, mi2, fg2, fbe2, ff_t, N, PN);

  // Szr[n'][128]: cols 0-63 = z-gate target scores, 64-127 = r-gate
  projT_kernel<<<dim3(PN / 64, 2), 256, 0, stream>>>(WtZR, 195, 128, bZR, Szr, N, PN,
      corr0, 64, 0,  ff_t, 64, 1,  state, 64, 0,  xyz0, 3, 0);

  gate_zr_kernel<<<dim3(256, B_SZ), 256, 0, stream>>>(Szr, wz, wr, xyz0, state, idx0, zg, rs_t, N, PN);

  projT_kernel<<<dim3(PN / 64, 1), 256, 0, stream>>>(WtQ, 195, 64, bq, Sq, N, PN,
      corr0, 64, 0,  ff_t, 64, 1,  rs_t, 64, 1,  xyz0, 3, 0);

  gate_q_ns_kernel<<<dim3(256, B_SZ), 256, 0, stream>>>(Sq, wq, xyz0, zg, state, idx0, ns, N);

  // U = wa1[:,:128]@feat0 + wa1[:,256:]@xyz0 ; V = wa1[:,128:256]@feat1 - wa1[:,256:]@xyz1 + ba1
  projT_kernel<<<dim3(PN / 64, 2), 256, 0, stream>>>(WtU, 131, 128, FN, U, N, PN,
      feat0, 128, 0,  xyz0, 3, 0,  FN, 0, 0,  FN, 0, 0);
  projT_kernel<<<dim3(PN / 64, 2), 256, 0, stream>>>(WtV, 131, 128, ba1, V, N, PN,
      feat1, 128, 0,  xyz1, 3, 0,  FN, 0, 0,  FN, 0, 0);

  align_kernel<<<dim3(N / 4, B_SZ), 256, 0, stream>>>(U, V, wa2, ba2, ns, idx1, out, N);
}

// Round 7
// 368.222 us; speedup vs baseline: 1.6482x; 1.1084x over previous
//
#include <hip/hip_runtime.h>

#define B_SZ 2

__device__ __forceinline__ int rfl(int x) { return __builtin_amdgcn_readfirstlane(x); }
__device__ __forceinline__ float leaky(float v) { return v >= 0.f ? v : 0.1f * v; }

// ---------------------------------------------------------------- KNN ----
// Pack targets: [B,3,N] -> [B,N] float4(x,y,z, x^2+y^2+z^2)  (FULL norm --
// must match rounds 2-5 FP formula exactly for boundary-stable selection)
__launch_bounds__(256)
__global__ void pack_kernel(const float* __restrict__ xyz, float4* __restrict__ out, int N)
{
  int b = blockIdx.y;
  int i = blockIdx.x * 256 + threadIdx.x;
  if (i >= N) return;
  const float* p = xyz + (size_t)b * 3 * N;
  float x = p[i], y = p[N + i], z = p[2 * N + i];
  out[(size_t)b * N + i] = make_float4(x, y, z, x * x + y * y + z * z);
}

// 64-lane bitonic sort ascending by (d, i)
__device__ __forceinline__ void sort64(float& d, int& i, int lane)
{
#pragma unroll
  for (int k = 2; k <= 64; k <<= 1) {
#pragma unroll
    for (int j = k >> 1; j > 0; j >>= 1) {
      float od = __shfl_xor(d, j, 64);
      int   oi = __shfl_xor(i, j, 64);
      bool mineSmall = (d < od) || (d == od && i < oi);
      bool amLow = (lane & j) == 0;
      bool up = (lane & k) == 0;
      bool keepMine = (amLow == up) ? mineSmall : !mineSmall;
      if (!keepMine) { d = od; i = oi; }
    }
  }
}

// One wave per query. Two-phase: (1) per-lane min -> certified threshold t0,
// (2) collect all keys <= t0 into LDS, then bitonic-select exact top-16.
__launch_bounds__(256)
__global__ void knn_wave_kernel(const float4* __restrict__ pk, const float* __restrict__ q,
                                int* __restrict__ idx, int N)
{
  __shared__ __align__(16) float4 ts[1024];
  __shared__ uint2 buf[4][256];
  const int b = blockIdx.y;
  const int lane = threadIdx.x & 63, wav = rfl(threadIdx.x >> 6);
  const int qi = blockIdx.x * 4 + wav;
  const float* qb = q + (size_t)b * 3 * N;
  const float qx = qb[qi], qy = qb[N + qi], qz = qb[2 * N + qi];
  const float qq = qx * qx + qy * qy + qz * qz;
  const float4* pb = pk + (size_t)b * N;

  // ---- pass 1: per-lane min of d = (qq + |t|^2) - 2 q.t  (round-5 formula)
  float lmin = 3.0e38f;
  for (int ch = 0; ch < N; ch += 1024) {
    __syncthreads();
    for (int i = threadIdx.x; i < 1024; i += 256) ts[i] = pb[ch + i];
    __syncthreads();
#pragma unroll 4
    for (int sub = 0; sub < 16; ++sub) {
      float4 v = ts[sub * 64 + lane];
      float key = (qq + v.w) - 2.0f * (qx * v.x + qy * v.y + qz * v.z);
      lmin = fminf(lmin, key);
    }
  }
  // group-of-4 min, then max over the 16 groups -> upper bound on 16th-smallest
  float gm = fminf(lmin, __shfl_xor(lmin, 1, 64));
  gm = fminf(gm, __shfl_xor(gm, 2, 64));
  float t0 = gm;
  t0 = fmaxf(t0, __shfl_xor(t0, 4, 64));
  t0 = fmaxf(t0, __shfl_xor(t0, 8, 64));
  t0 = fmaxf(t0, __shfl_xor(t0, 16, 64));
  t0 = fmaxf(t0, __shfl_xor(t0, 32, 64));

  // ---- pass 2: warp-aggregated collect of qualifiers (key <= t0)
  int cnt = 0;
  for (int ch = 0; ch < N; ch += 1024) {
    __syncthreads();
    for (int i = threadIdx.x; i < 1024; i += 256) ts[i] = pb[ch + i];
    __syncthreads();
    for (int sub = 0; sub < 16; ++sub) {
      float4 v = ts[sub * 64 + lane];
      float key = (qq + v.w) - 2.0f * (qx * v.x + qy * v.y + qz * v.z);
      bool qf = key <= t0;
      unsigned long long mask = __ballot(qf);
      if (mask) {
        unsigned lo = __builtin_amdgcn_mbcnt_lo((unsigned)mask, 0u);
        unsigned pre = __builtin_amdgcn_mbcnt_hi((unsigned)(mask >> 32), lo);
        if (qf) {
          unsigned slot = (unsigned)cnt + pre;
          if (slot < 256u)
            buf[wav][slot] = make_uint2(__float_as_uint(key), (unsigned)(ch + sub * 64 + lane));
        }
        cnt += (int)__popcll(mask);
      }
    }
  }
  int C = cnt < 256 ? cnt : 256;

  // ---- exact select: bitonic sort collected, keep 16 smallest
  float kd = 3.0e38f; int ki = 0x7fffffff;
  if (lane < C) { uint2 u = buf[wav][lane]; kd = __uint_as_float(u.x); ki = (int)u.y; }
  sort64(kd, ki, lane);
  int consumed = C < 64 ? C : 64;
  while (consumed < C) {
    if (lane >= 16) {
      int j2 = consumed + (lane - 16);
      if (j2 < C) { uint2 u = buf[wav][j2]; kd = __uint_as_float(u.x); ki = (int)u.y; }
      else { kd = 3.0e38f; ki = 0x7fffffff; }
    }
    int t = C - consumed; consumed += (t < 48 ? t : 48);
    sort64(kd, ki, lane);
  }
  if (lane < 16) idx[((size_t)b * N + qi) * 16 + lane] = ki;
}

// -------------------------------------------------- weight pre-transpose ----
__launch_bounds__(256)
__global__ void prep_w_kernel(const float* __restrict__ wz, const float* __restrict__ wr,
    const float* __restrict__ wq, const float* __restrict__ wa1,
    const float* __restrict__ bz, const float* __restrict__ br,
    float* __restrict__ WtZR, float* __restrict__ WtQ,
    float* __restrict__ WtU, float* __restrict__ WtV, float* __restrict__ bZR)
{
  int job = blockIdx.x;
  int tid = threadIdx.x;
  if (job == 0) {                      // WtZR [195][128]: o<64 -> wz row, else wr
    for (int e = tid; e < 195 * 128; e += 256) {
      int k = e >> 7, o = e & 127;
      const float* w = (o < 64) ? wz : wr;
      WtZR[(size_t)k * 128 + o] = w[(size_t)(o & 63) * 195 + k];
    }
    if (tid < 128) bZR[tid] = (tid < 64) ? bz[tid] : br[tid - 64];
  } else if (job == 1) {               // WtQ [195][64]
    for (int e = tid; e < 195 * 64; e += 256) {
      int k = e >> 6, o = e & 63;
      WtQ[(size_t)k * 64 + o] = wq[(size_t)o * 195 + k];
    }
  } else if (job == 2) {               // WtU [131][128]
    for (int e = tid; e < 131 * 128; e += 256) {
      int k = e >> 7, o = e & 127;
      int col = (k < 128) ? k : 256 + (k - 128);
      WtU[(size_t)k * 128 + o] = wa1[(size_t)o * 259 + col];
    }
  } else {                             // WtV [131][128]
    for (int e = tid; e < 131 * 128; e += 256) {
      int k = e >> 7, o = e & 127;
      float v = (k < 128) ? wa1[(size_t)o * 259 + 128 + k]
                          : -wa1[(size_t)o * 259 + 256 + (k - 128)];
      WtV[(size_t)k * 128 + o] = v;
    }
  }
}

// -------------------------------------------------- tiled projection GEMM ----
#define KC 66
__launch_bounds__(256)
__global__ void projT_kernel(const float* __restrict__ Wt, int K, int WOUT,
    const float* __restrict__ bias, float* __restrict__ out,
    int N, int PN,
    const float* __restrict__ s0, int c0, int l0,
    const float* __restrict__ s1, int c1, int l1,
    const float* __restrict__ s2, int c2, int l2,
    const float* __restrict__ s3, int c3, int l3)
{
  __shared__ __align__(16) float Ws[KC][68];
  __shared__ __align__(16) float Xs[KC][68];
  const int n0 = blockIdx.x * 64;
  const int oo = blockIdx.y * 64;
  const int b = n0 / N;
  const int nn0 = n0 - b * N;
  const int tid = threadIdx.x;
  const int tx = tid & 15, ty = tid >> 4;
  const int o4 = tx * 4, n4 = ty * 4;
  float acc[4][4];
#pragma unroll
  for (int i = 0; i < 4; ++i)
#pragma unroll
    for (int j = 0; j < 4; ++j)
      acc[i][j] = bias ? bias[oo + o4 + j] : 0.0f;

  const int e01 = c0 + c1, e012 = c0 + c1 + c2;
  for (int k0 = 0; k0 < K; k0 += KC) {
    const int kc = min(KC, K - k0);
    __syncthreads();
    for (int e = tid; e < kc * 64; e += 256) {
      int k = e >> 6, o = e & 63;
      Ws[k][o] = Wt[(size_t)(k0 + k) * WOUT + oo + o];
    }
    for (int e = tid; e < kc * 64; e += 256) {
      int k = e >> 6, j = e & 63;
      int c = k0 + k;
      float v;
      if (c < c0)        v = l0 ? s0[(size_t)c * PN + n0 + j]
                                : s0[((size_t)b * c0 + c) * N + nn0 + j];
      else if (c < e01)  { int cc = c - c0;
                           v = l1 ? s1[(size_t)cc * PN + n0 + j]
                                  : s1[((size_t)b * c1 + cc) * N + nn0 + j]; }
      else if (c < e012) { int cc = c - e01;
                           v = l2 ? s2[(size_t)cc * PN + n0 + j]
                                  : s2[((size_t)b * c2 + cc) * N + nn0 + j]; }
      else               { int cc = c - e012;
                           v = l3 ? s3[(size_t)cc * PN + n0 + j]
                                  : s3[((size_t)b * c3 + cc) * N + nn0 + j]; }
      Xs[k][j] = v;
    }
    __syncthreads();
#pragma unroll 2
    for (int k = 0; k < kc; ++k) {
      float4 wv = *(const float4*)&Ws[k][o4];
      float4 xv = *(const float4*)&Xs[k][n4];
      acc[0][0] = fmaf(xv.x, wv.x, acc[0][0]); acc[0][1] = fmaf(xv.x, wv.y, acc[0][1]);
      acc[0][2] = fmaf(xv.x, wv.z, acc[0][2]); acc[0][3] = fmaf(xv.x, wv.w, acc[0][3]);
      acc[1][0] = fmaf(xv.y, wv.x, acc[1][0]); acc[1][1] = fmaf(xv.y, wv.y, acc[1][1]);
      acc[1][2] = fmaf(xv.y, wv.z, acc[1][2]); acc[1][3] = fmaf(xv.y, wv.w, acc[1][3]);
      acc[2][0] = fmaf(xv.z, wv.x, acc[2][0]); acc[2][1] = fmaf(xv.z, wv.y, acc[2][1]);
      acc[2][2] = fmaf(xv.z, wv.z, acc[2][2]); acc[2][3] = fmaf(xv.z, wv.w, acc[2][3]);
      acc[3][0] = fmaf(xv.w, wv.x, acc[3][0]); acc[3][1] = fmaf(xv.w, wv.y, acc[3][1]);
      acc[3][2] = fmaf(xv.w, wv.z, acc[3][2]); acc[3][3] = fmaf(xv.w, wv.w, acc[3][3]);
    }
  }
#pragma unroll
  for (int i = 0; i < 4; ++i) {
    float4 r = make_float4(acc[i][0], acc[i][1], acc[i][2], acc[i][3]);
    *(float4*)&out[(size_t)(n0 + n4 + i) * WOUT + oo + o4] = r;
  }
}

// --------------------------------------------------------- small proj (G1) ----
__device__ __forceinline__ void seg_accumL(const float* __restrict__ p, int cnt,
    const float* __restrict__ WL, int sC, int sN, long n0, float acc[4])
{
#pragma unroll 4
  for (int c = 0; c < cnt; ++c) {
    float w = WL[c];
    const float* pp = p + (size_t)c * sC + (size_t)n0 * sN;
#pragma unroll
    for (int m = 0; m < 4; ++m)
      acc[m] = fmaf(w, pp[(size_t)m * sN], acc[m]);
  }
}

template<int WP>
__launch_bounds__(256)
__global__ void proj_kernel(
    const float* __restrict__ W0, const float* __restrict__ bias,
    float* __restrict__ out, int OUTS, int wld, int N,
    const float* __restrict__ s0, int c0, int w0,
    const float* __restrict__ s1, int c1, int w1)
{
  __shared__ float Wl[64 * WP];
  const int b = blockIdx.y;
  const int lane = threadIdx.x & 63;
  const int wav = rfl(threadIdx.x >> 6);
  for (int r = wav; r < 64; r += 4)
    for (int c = lane; c < c0; c += 64)
      Wl[r * WP + c] = W0[(size_t)r * wld + w0 + c];
  for (int r = wav; r < 64; r += 4)
    for (int c = lane; c < c1; c += 64)
      Wl[r * WP + c0 + c] = W0[(size_t)r * wld + w1 + c];
  __syncthreads();
  const long n0 = ((long)blockIdx.x * 4 + wav) * 4;
  float bv = bias ? bias[lane] : 0.0f;
  float acc[4] = {bv, bv, bv, bv};
  const float* WL = &Wl[lane * WP];
  seg_accumL(s0 + (size_t)b * c0 * N, c0, WL, N, 1, n0, acc);
  seg_accumL(s1 + (size_t)b * c1 * N, c1, WL + c0, N, 1, n0, acc);
#pragma unroll
  for (int m = 0; m < 4; ++m)
    out[((size_t)b * N + n0 + m) * OUTS + lane] = acc[m];
}

// ------------------------------------------------------------- groupnorm ----
__launch_bounds__(256)
__global__ void gn1_stats_kernel(const float* __restrict__ G1, const float* __restrict__ xyz0,
    const float* __restrict__ fw1, const int* __restrict__ idx0,
    float* __restrict__ stats1, int N)
{
  __shared__ float red[4][4][2];
  int b = blockIdx.y;
  int lane = threadIdx.x & 63, wav = rfl(threadIdx.x >> 6);
  float wg0 = fw1[lane * 6 + 3], wg1 = fw1[lane * 6 + 4], wg2 = fw1[lane * 6 + 5];
  const float* xb = xyz0 + (size_t)b * 3 * N;
  float sum = 0.f, sq = 0.f;
  for (int n = blockIdx.x * 4 + wav; n < N; n += gridDim.x * 4) {
    const int* ip = idx0 + ((size_t)b * N + n) * 16;
    float bx = wg0 * xb[n] + wg1 * xb[N + n] + wg2 * xb[2 * N + n];
#pragma unroll
    for (int k = 0; k < 16; ++k) {
      int m = ip[k];
      float y = G1[((size_t)b * N + m) * 64 + lane] - bx;
      sum += y; sq += y * y;
    }
  }
#pragma unroll
  for (int off = 1; off < 16; off <<= 1) {
    sum += __shfl_xor(sum, off, 64);
    sq += __shfl_xor(sq, off, 64);
  }
  int g = lane >> 4;
  if ((lane & 15) == 0) { red[wav][g][0] = sum; red[wav][g][1] = sq; }
  __syncthreads();
  if (threadIdx.x < 8) {
    int gg = threadIdx.x >> 1, s = threadIdx.x & 1;
    float v = red[0][gg][s] + red[1][gg][s] + red[2][gg][s] + red[3][gg][s];
    atomicAdd(&stats1[(b * 4 + gg) * 2 + s], v);
  }
}

__global__ void gn_finalize_kernel(const float* __restrict__ raw, float* __restrict__ mi, float cnt)
{
  int i = threadIdx.x;
  if (i < 8) {
    float s = raw[i * 2], q = raw[i * 2 + 1];
    float m = s / cnt;
    float v = q / cnt - m * m;
    mi[i * 2] = m;
    mi[i * 2 + 1] = rsqrtf(v + 1e-5f);
  }
}

// ------------------------------------------------------------- flow conv2 ----
__launch_bounds__(256, 2)
__global__ void conv2_kernel(const float* __restrict__ G1, const float* __restrict__ xyz0,
    const float* __restrict__ fw1, const int* __restrict__ idx0,
    const float* __restrict__ fw2, const float* __restrict__ fb2,
    const float* __restrict__ fg1, const float* __restrict__ fbe1,
    const float* __restrict__ mi1, float* __restrict__ y2max, float* __restrict__ y2min,
    float* __restrict__ stats2, int N)
{
  __shared__ __align__(16) float x2[4][16][64];
  __shared__ float red[4][4][2];
  const int b = blockIdx.y;
  const int lane = threadIdx.x & 63;
  const int wav = rfl(threadIdx.x >> 6);
  float4 w[16];
#pragma unroll
  for (int i = 0; i < 16; ++i) w[i] = *(const float4*)&fw2[lane * 64 + i * 4];
  float wg0 = fw1[lane * 6 + 3], wg1 = fw1[lane * 6 + 4], wg2 = fw1[lane * 6 + 5];
  const int g = lane >> 4;
  float mu1 = mi1[(b * 4 + g) * 2], inv1 = mi1[(b * 4 + g) * 2 + 1];
  float sc1 = fg1[lane] * inv1;
  float sh1 = fbe1[lane] - mu1 * sc1;
  float fb2l = fb2[lane];
  const float* xb = xyz0 + (size_t)b * 3 * N;
  float sum = 0.f, sq = 0.f;
  for (int n = blockIdx.x * 4 + wav; n < N; n += gridDim.x * 4) {
    const int* ip = idx0 + ((size_t)b * N + n) * 16;
    float bx = wg0 * xb[n] + wg1 * xb[N + n] + wg2 * xb[2 * N + n];
#pragma unroll
    for (int k = 0; k < 16; ++k) {
      int m = ip[k];
      float y = G1[((size_t)b * N + m) * 64 + lane] - bx;
      x2[wav][k][lane] = leaky(y * sc1 + sh1);
    }
    float acc[16];
#pragma unroll
    for (int k = 0; k < 16; ++k) acc[k] = fb2l;
#pragma unroll
    for (int c4 = 0; c4 < 16; ++c4) {
      float4 w4 = w[c4];
#pragma unroll
      for (int k = 0; k < 16; ++k) {
        float4 x4 = *(const float4*)&x2[wav][k][c4 * 4];
        acc[k] = fmaf(w4.x, x4.x, acc[k]);
        acc[k] = fmaf(w4.y, x4.y, acc[k]);
        acc[k] = fmaf(w4.z, x4.z, acc[k]);
        acc[k] = fmaf(w4.w, x4.w, acc[k]);
      }
    }
    float mx = -3.0e38f, mn = 3.0e38f;
#pragma unroll
    for (int k = 0; k < 16; ++k) {
      mx = fmaxf(mx, acc[k]); mn = fminf(mn, acc[k]);
      sum += acc[k]; sq += acc[k] * acc[k];
    }
    y2max[((size_t)b * N + n) * 64 + lane] = mx;
    y2min[((size_t)b * N + n) * 64 + lane] = mn;
  }
#pragma unroll
  for (int off = 1; off < 16; off <<= 1) {
    sum += __shfl_xor(sum, off, 64);
    sq += __shfl_xor(sq, off, 64);
  }
  if ((lane & 15) == 0) { red[wav][g][0] = sum; red[wav][g][1] = sq; }
  __syncthreads();
  if (threadIdx.x < 8) {
    int gg = threadIdx.x >> 1, s = threadIdx.x & 1;
    float v = red[0][gg][s] + red[1][gg][s] + red[2][gg][s] + red[3][gg][s];
    atomicAdd(&stats2[(b * 4 + gg) * 2 + s], v);
  }
}

__launch_bounds__(256)
__global__ void flow_feat_kernel(const float* __restrict__ y2max, const float* __restrict__ y2min,
    const float* __restrict__ mi2, const float* __restrict__ fg2, const float* __restrict__ fbe2,
    float* __restrict__ ff_t, int N, int PN)
{
  size_t i = (size_t)blockIdx.x * blockDim.x + threadIdx.x;
  if (i >= (size_t)B_SZ * N * 64) return;
  int c = i & 63;
  size_t pn = i >> 6;
  int b = (int)(pn / N);
  int g = c >> 4;
  float mu = mi2[(b * 4 + g) * 2], inv = mi2[(b * 4 + g) * 2 + 1];
  float sc = fg2[c] * inv;
  float sh = fbe2[c] - mu * sc;
  float y = (sc >= 0.0f) ? y2max[i] : y2min[i];
  ff_t[(size_t)c * PN + pn] = leaky(y * sc + sh);
}

// ------------------------------------------------------------------ gates ----
__launch_bounds__(256)
__global__ void gate_zr_kernel(const float* __restrict__ Szr,
    const float* __restrict__ wz, const float* __restrict__ wr,
    const float* __restrict__ xyz0, const float* __restrict__ state,
    const int* __restrict__ idx0,
    float* __restrict__ zo, float* __restrict__ rs_t, int N, int PN)
{
  int b = blockIdx.y;
  int lane = threadIdx.x & 63, wav = rfl(threadIdx.x >> 6);
  float wz0 = wz[lane * 195 + 192], wz1 = wz[lane * 195 + 193], wz2 = wz[lane * 195 + 194];
  float wr0 = wr[lane * 195 + 192], wr1 = wr[lane * 195 + 193], wr2 = wr[lane * 195 + 194];
  const float* xb = xyz0 + (size_t)b * 3 * N;
  for (int n = blockIdx.x * 4 + wav; n < N; n += gridDim.x * 4) {
    const int* ip = idx0 + ((size_t)b * N + n) * 16;
    float u0 = xb[n], u1 = xb[N + n], u2 = xb[2 * N + n];
    float xz = wz0 * u0 + wz1 * u1 + wz2 * u2;
    float xr = wr0 * u0 + wr1 * u1 + wr2 * u2;
    float mz = -3.0e38f, mr = -3.0e38f;
#pragma unroll
    for (int k = 0; k < 16; ++k) {
      size_t mo = ((size_t)b * N + ip[k]) * 128 + lane;
      mz = fmaxf(mz, Szr[mo]);
      mr = fmaxf(mr, Szr[mo + 64]);
    }
    size_t no = ((size_t)b * N + n) * 64 + lane;
    float z = 1.f / (1.f + expf(-(mz - xz)));
    float r = 1.f / (1.f + expf(-(mr - xr)));
    zo[no] = z;
    rs_t[(size_t)lane * PN + (size_t)b * N + n] = r * state[((size_t)b * 64 + lane) * N + n];
  }
}

__launch_bounds__(256)
__global__ void gate_q_ns_kernel(const float* __restrict__ Sq, const float* __restrict__ wq,
    const float* __restrict__ xyz0, const float* __restrict__ zo,
    const float* __restrict__ state, const int* __restrict__ idx0,
    float* __restrict__ ns, int N)
{
  int b = blockIdx.y;
  int lane = threadIdx.x & 63, wav = rfl(threadIdx.x >> 6);
  float wq0 = wq[lane * 195 + 192], wq1 = wq[lane * 195 + 193], wq2 = wq[lane * 195 + 194];
  const float* xb = xyz0 + (size_t)b * 3 * N;
  for (int n = blockIdx.x * 4 + wav; n < N; n += gridDim.x * 4) {
    const int* ip = idx0 + ((size_t)b * N + n) * 16;
    float xq = wq0 * xb[n] + wq1 * xb[N + n] + wq2 * xb[2 * N + n];
    float mq = -3.0e38f;
#pragma unroll
    for (int k = 0; k < 16; ++k)
      mq = fmaxf(mq, Sq[((size_t)b * N + ip[k]) * 64 + lane]);
    size_t no = ((size_t)b * N + n) * 64 + lane;
    float q = tanhf(mq - xq);
    float z = zo[no];
    float st = state[((size_t)b * 64 + lane) * N + n];
    ns[no] = (1.f - z) * st + z * q;
  }
}

// ------------------------------------------------------------------ align ----
__launch_bounds__(256, 2)
__global__ void align_kernel(const float* __restrict__ U, const float* __restrict__ V,
    const float* __restrict__ wa2, const float* __restrict__ ba2,
    const float* __restrict__ ns, const int* __restrict__ idx1,
    float* __restrict__ out, int N)
{
  __shared__ __align__(16) float xk[4][16][128];
  const int b = blockIdx.y;
  const int lane = threadIdx.x & 63;
  const int wav = rfl(threadIdx.x >> 6);
  float4 w[32];
#pragma unroll
  for (int i = 0; i < 32; ++i) w[i] = *(const float4*)&wa2[lane * 128 + i * 4];
  float ba = ba2[lane];
  const int n = blockIdx.x * 4 + wav;
  const int* ip = idx1 + ((size_t)b * N + n) * 16;
  int mk[16];
#pragma unroll
  for (int k = 0; k < 16; ++k) mk[k] = ip[k];
  const float* Vp = V + ((size_t)b * N + n) * 128;
  float v0 = Vp[lane], v1 = Vp[64 + lane];
#pragma unroll
  for (int k = 0; k < 16; ++k) {
    const float* Up = U + ((size_t)b * N + mk[k]) * 128;
    xk[wav][k][lane] = leaky(Up[lane] + v0);
    xk[wav][k][64 + lane] = leaky(Up[64 + lane] + v1);
  }
  float acc[16];
#pragma unroll
  for (int k = 0; k < 16; ++k) acc[k] = ba;
#pragma unroll
  for (int c4 = 0; c4 < 32; ++c4) {
    float4 w4 = w[c4];
#pragma unroll
    for (int k = 0; k < 16; ++k) {
      float4 x4 = *(const float4*)&xk[wav][k][c4 * 4];
      acc[k] = fmaf(w4.x, x4.x, acc[k]);
      acc[k] = fmaf(w4.y, x4.y, acc[k]);
      acc[k] = fmaf(w4.z, x4.z, acc[k]);
      acc[k] = fmaf(w4.w, x4.w, acc[k]);
    }
  }
  float m = acc[0];
#pragma unroll
  for (int k = 1; k < 16; ++k) m = fmaxf(m, acc[k]);
  float s = 0.f;
#pragma unroll
  for (int k = 0; k < 16; ++k) { acc[k] = expf(acc[k] - m); s += acc[k]; }
  float rinv = 1.0f / s;
  float o = 0.f;
#pragma unroll
  for (int k = 0; k < 16; ++k)
    o += acc[k] * rinv * ns[((size_t)b * N + mk[k]) * 64 + lane];
  out[((size_t)b * 64 + lane) * N + n] = o;
}

// ------------------------------------------------------------------ launch ----
extern "C" void kernel_launch(void* const* d_in, const int* in_sizes, int n_in,
                              void* d_out, int out_size, void* d_ws, size_t ws_size,
                              hipStream_t stream) {
  (void)n_in; (void)out_size; (void)ws_size;
  const float* xyz0 = (const float*)d_in[0];
  const float* xyz1 = (const float*)d_in[1];
  const float* state = (const float*)d_in[2];
  const float* corr0 = (const float*)d_in[3];
  const float* feat0 = (const float*)d_in[4];
  const float* feat1 = (const float*)d_in[5];
  const float* flow0 = (const float*)d_in[6];
  const float* fw1 = (const float*)d_in[7];
  const float* fb1 = (const float*)d_in[8];
  const float* fg1 = (const float*)d_in[9];
  const float* fbe1 = (const float*)d_in[10];
  const float* fw2 = (const float*)d_in[11];
  const float* fb2 = (const float*)d_in[12];
  const float* fg2 = (const float*)d_in[13];
  const float* fbe2 = (const float*)d_in[14];
  const float* wz = (const float*)d_in[15];
  const float* bz = (const float*)d_in[16];
  const float* wr = (const float*)d_in[17];
  const float* br = (const float*)d_in[18];
  const float* wq = (const float*)d_in[19];
  const float* bq = (const float*)d_in[20];
  const float* wa1 = (const float*)d_in[21];
  const float* ba1 = (const float*)d_in[22];
  const float* wa2 = (const float*)d_in[23];
  const float* ba2 = (const float*)d_in[24];
  float* out = (float*)d_out;

  const int N = in_sizes[0] / (3 * B_SZ);  // 4096
  const int PN = B_SZ * N;                 // 8192
  char* wsb = (char*)d_ws;
  size_t off = 0;
  auto take = [&](size_t bytes) -> char* {
    char* p = wsb + off;
    off += (bytes + 255) & ~(size_t)255;
    return p;
  };
  float* U    = (float*)take((size_t)PN * 128 * 4);
  float* V    = (float*)take((size_t)PN * 128 * 4);
  float* Szr  = (float*)take((size_t)PN * 128 * 4);
  float4* pk0 = (float4*)take((size_t)PN * 4 * 4);
  int*   idx0 = (int*)  take((size_t)PN * 16 * 4);
  int*   idx1 = (int*)  take((size_t)PN * 16 * 4);
  float* G1   = (float*)take((size_t)PN * 64 * 4);
  float* y2mx = (float*)take((size_t)PN * 64 * 4);
  float* y2mn = (float*)take((size_t)PN * 64 * 4);
  float* ff_t = (float*)take((size_t)PN * 64 * 4);
  float* Sq   = (float*)take((size_t)PN * 64 * 4);
  float* zg   = (float*)take((size_t)PN * 64 * 4);
  float* rs_t = (float*)take((size_t)PN * 64 * 4);
  float* ns   = (float*)take((size_t)PN * 64 * 4);
  float* WtZR = (float*)take(195 * 128 * 4);
  float* WtQ  = (float*)take(195 * 64 * 4);
  float* WtU  = (float*)take(131 * 128 * 4);
  float* WtV  = (float*)take(131 * 128 * 4);
  float* bZR  = (float*)take(128 * 4);
  float* stats = (float*)take(256);
  float* raw1 = stats, *raw2 = stats + 16, *mi1 = stats + 32, *mi2 = stats + 48;

  const float* FN = nullptr;
  const float cntv = 16.0f * N * 16.0f;

  hipMemsetAsync(raw1, 0, 32 * sizeof(float), stream);

  pack_kernel<<<dim3((N + 255) / 256, B_SZ), 256, 0, stream>>>(xyz0, pk0, N);
  prep_w_kernel<<<4, 256, 0, stream>>>(wz, wr, wq, wa1, bz, br, WtZR, WtQ, WtU, WtV, bZR);
  knn_wave_kernel<<<dim3(N / 4, B_SZ), 256, 0, stream>>>(pk0, xyz0, idx0, N);
  knn_wave_kernel<<<dim3(N / 4, B_SZ), 256, 0, stream>>>(pk0, xyz1, idx1, N);

  // G1 = fw1[:,:3]@flow0 + fw1[:,3:]@xyz0 + fb1
  proj_kernel<7><<<dim3(N / 16, B_SZ), 256, 0, stream>>>(
      fw1, fb1, G1, 64, 6, N, flow0, 3, 0, xyz0, 3, 3);

  gn1_stats_kernel<<<dim3(256, B_SZ), 256, 0, stream>>>(G1, xyz0, fw1, idx0, raw1, N);
  gn_finalize_kernel<<<1, 64, 0, stream>>>(raw1, mi1, cntv);
  conv2_kernel<<<dim3(512, B_SZ), 256, 0, stream>>>(G1, xyz0, fw1, idx0, fw2, fb2, fg1, fbe1,
      mi1, y2mx, y2mn, raw2, N);
  gn_finalize_kernel<<<1, 64, 0, stream>>>(raw2, mi2, cntv);
  flow_feat_kernel<<<dim3((unsigned)((size_t)PN * 64 / 256)), 256, 0, stream>>>(
      y2mx, y2mn, mi2, fg2, fbe2, ff_t, N, PN);

  // Szr[n'][128]: cols 0-63 = z-gate target scores, 64-127 = r-gate
  projT_kernel<<<dim3(PN / 64, 2), 256, 0, stream>>>(WtZR, 195, 128, bZR, Szr, N, PN,
      corr0, 64, 0,  ff_t, 64, 1,  state, 64, 0,  xyz0, 3, 0);

  gate_zr_kernel<<<dim3(256, B_SZ), 256, 0, stream>>>(Szr, wz, wr, xyz0, state, idx0, zg, rs_t, N, PN);

  projT_kernel<<<dim3(PN / 64, 1), 256, 0, stream>>>(WtQ, 195, 64, bq, Sq, N, PN,
      corr0, 64, 0,  ff_t, 64, 1,  rs_t, 64, 1,  xyz0, 3, 0);

  gate_q_ns_kernel<<<dim3(256, B_SZ), 256, 0, stream>>>(Sq, wq, xyz0, zg, state, idx0, ns, N);

  // U = wa1[:,:128]@feat0 + wa1[:,256:]@xyz0 ; V = wa1[:,128:256]@feat1 - wa1[:,256:]@xyz1 + ba1
  projT_kernel<<<dim3(PN / 64, 2), 256, 0, stream>>>(WtU, 131, 128, FN, U, N, PN,
      feat0, 128, 0,  xyz0, 3, 0,  FN, 0, 0,  FN, 0, 0);
  projT_kernel<<<dim3(PN / 64, 2), 256, 0, stream>>>(WtV, 131, 128, ba1, V, N, PN,
      feat1, 128, 0,  xyz1, 3, 0,  FN, 0, 0,  FN, 0, 0);

  align_kernel<<<dim3(N / 4, B_SZ), 256, 0, stream>>>(U, V, wa2, ba2, ns, idx1, out, N);
}

// Round 9
// 337.840 us; speedup vs baseline: 1.7964x; 1.0899x over previous
//
#include <hip/hip_runtime.h>

#define B_SZ 2

__device__ __forceinline__ int rfl(int x) { return __builtin_amdgcn_readfirstlane(x); }
__device__ __forceinline__ float leaky(float v) { return v >= 0.f ? v : 0.1f * v; }

// ---------------------------------------------------------------- KNN ----
__launch_bounds__(256)
__global__ void pack_kernel(const float* __restrict__ xyz, float4* __restrict__ out, int N)
{
  int b = blockIdx.y;
  int i = blockIdx.x * 256 + threadIdx.x;
  if (i >= N) return;
  const float* p = xyz + (size_t)b * 3 * N;
  float x = p[i], y = p[N + i], z = p[2 * N + i];
  out[(size_t)b * N + i] = make_float4(x, y, z, x * x + y * y + z * z);
}

// 64-lane bitonic sort ascending by (d, i)
__device__ __forceinline__ void sort64(float& d, int& i, int lane)
{
#pragma unroll
  for (int k = 2; k <= 64; k <<= 1) {
#pragma unroll
    for (int j = k >> 1; j > 0; j >>= 1) {
      float od = __shfl_xor(d, j, 64);
      int   oi = __shfl_xor(i, j, 64);
      bool mineSmall = (d < od) || (d == od && i < oi);
      bool amLow = (lane & j) == 0;
      bool up = (lane & k) == 0;
      bool keepMine = (amLow == up) ? mineSmall : !mineSmall;
      if (!keepMine) { d = od; i = oi; }
    }
  }
}

__launch_bounds__(256)
__global__ void knn_wave_kernel(const float4* __restrict__ pk, const float* __restrict__ q,
                                int* __restrict__ idx, int N)
{
  __shared__ __align__(16) float4 ts[1024];
  __shared__ uint2 buf[4][256];
  const int b = blockIdx.y;
  const int lane = threadIdx.x & 63, wav = rfl(threadIdx.x >> 6);
  const int qi = blockIdx.x * 4 + wav;
  const float* qb = q + (size_t)b * 3 * N;
  const float qx = qb[qi], qy = qb[N + qi], qz = qb[2 * N + qi];
  const float qq = qx * qx + qy * qy + qz * qz;
  const float4* pb = pk + (size_t)b * N;

  float lmin = 3.0e38f;
  for (int ch = 0; ch < N; ch += 1024) {
    __syncthreads();
    for (int i = threadIdx.x; i < 1024; i += 256) ts[i] = pb[ch + i];
    __syncthreads();
#pragma unroll 4
    for (int sub = 0; sub < 16; ++sub) {
      float4 v = ts[sub * 64 + lane];
      float key = (qq + v.w) - 2.0f * (qx * v.x + qy * v.y + qz * v.z);
      lmin = fminf(lmin, key);
    }
  }
  float gm = fminf(lmin, __shfl_xor(lmin, 1, 64));
  gm = fminf(gm, __shfl_xor(gm, 2, 64));
  float t0 = gm;
  t0 = fmaxf(t0, __shfl_xor(t0, 4, 64));
  t0 = fmaxf(t0, __shfl_xor(t0, 8, 64));
  t0 = fmaxf(t0, __shfl_xor(t0, 16, 64));
  t0 = fmaxf(t0, __shfl_xor(t0, 32, 64));

  int cnt = 0;
  for (int ch = 0; ch < N; ch += 1024) {
    __syncthreads();
    for (int i = threadIdx.x; i < 1024; i += 256) ts[i] = pb[ch + i];
    __syncthreads();
    for (int sub = 0; sub < 16; ++sub) {
      float4 v = ts[sub * 64 + lane];
      float key = (qq + v.w) - 2.0f * (qx * v.x + qy * v.y + qz * v.z);
      bool qf = key <= t0;
      unsigned long long mask = __ballot(qf);
      if (mask) {
        unsigned lo = __builtin_amdgcn_mbcnt_lo((unsigned)mask, 0u);
        unsigned pre = __builtin_amdgcn_mbcnt_hi((unsigned)(mask >> 32), lo);
        if (qf) {
          unsigned slot = (unsigned)cnt + pre;
          if (slot < 256u)
            buf[wav][slot] = make_uint2(__float_as_uint(key), (unsigned)(ch + sub * 64 + lane));
        }
        cnt += (int)__popcll(mask);
      }
    }
  }
  int C = cnt < 256 ? cnt : 256;

  float kd = 3.0e38f; int ki = 0x7fffffff;
  if (lane < C) { uint2 u = buf[wav][lane]; kd = __uint_as_float(u.x); ki = (int)u.y; }
  sort64(kd, ki, lane);
  int consumed = C < 64 ? C : 64;
  while (consumed < C) {
    if (lane >= 16) {
      int j2 = consumed + (lane - 16);
      if (j2 < C) { uint2 u = buf[wav][j2]; kd = __uint_as_float(u.x); ki = (int)u.y; }
      else { kd = 3.0e38f; ki = 0x7fffffff; }
    }
    int t = C - consumed; consumed += (t < 48 ? t : 48);
    sort64(kd, ki, lane);
  }
  if (lane < 16) idx[((size_t)b * N + qi) * 16 + lane] = ki;
}

// -------------------------------------------------- weight pre-transpose ----
__launch_bounds__(256)
__global__ void prep_w_kernel(const float* __restrict__ wz, const float* __restrict__ wr,
    const float* __restrict__ wq, const float* __restrict__ wa1, const float* __restrict__ wa2,
    const float* __restrict__ bz, const float* __restrict__ br,
    float* __restrict__ WtZR, float* __restrict__ WtQ,
    float* __restrict__ WtU, float* __restrict__ WtV, float* __restrict__ WtA2,
    float* __restrict__ bZR)
{
  int job = blockIdx.x;
  int tid = threadIdx.x;
  if (job == 0) {                      // WtZR [195][128]
    for (int e = tid; e < 195 * 128; e += 256) {
      int k = e >> 7, o = e & 127;
      const float* w = (o < 64) ? wz : wr;
      WtZR[(size_t)k * 128 + o] = w[(size_t)(o & 63) * 195 + k];
    }
    if (tid < 128) bZR[tid] = (tid < 64) ? bz[tid] : br[tid - 64];
  } else if (job == 1) {               // WtQ [195][64]
    for (int e = tid; e < 195 * 64; e += 256) {
      int k = e >> 6, o = e & 63;
      WtQ[(size_t)k * 64 + o] = wq[(size_t)o * 195 + k];
    }
  } else if (job == 2) {               // WtU [131][128]
    for (int e = tid; e < 131 * 128; e += 256) {
      int k = e >> 7, o = e & 127;
      int col = (k < 128) ? k : 256 + (k - 128);
      WtU[(size_t)k * 128 + o] = wa1[(size_t)o * 259 + col];
    }
  } else if (job == 3) {               // WtV [131][128]
    for (int e = tid; e < 131 * 128; e += 256) {
      int k = e >> 7, o = e & 127;
      float v = (k < 128) ? wa1[(size_t)o * 259 + 128 + k]
                          : -wa1[(size_t)o * 259 + 256 + (k - 128)];
      WtV[(size_t)k * 128 + o] = v;
    }
  } else {                             // WtA2 [128][64] = wa2^T
    for (int e = tid; e < 128 * 64; e += 256) {
      int c = e >> 6, o = e & 63;
      WtA2[e] = wa2[(size_t)o * 128 + c];
    }
  }
}

// -------------------------------------------------- tiled projection GEMM ----
#define KC 66
__launch_bounds__(256)
__global__ void projT_kernel(const float* __restrict__ Wt, int K, int WOUT,
    const float* __restrict__ bias, float* __restrict__ out,
    int N, int PN,
    const float* __restrict__ s0, int c0, int l0,
    const float* __restrict__ s1, int c1, int l1,
    const float* __restrict__ s2, int c2, int l2,
    const float* __restrict__ s3, int c3, int l3)
{
  __shared__ __align__(16) float Ws[KC][68];
  __shared__ __align__(16) float Xs[KC][68];
  const int n0 = blockIdx.x * 64;
  const int oo = blockIdx.y * 64;
  const int b = n0 / N;
  const int nn0 = n0 - b * N;
  const int tid = threadIdx.x;
  const int tx = tid & 15, ty = tid >> 4;
  const int o4 = tx * 4, n4 = ty * 4;
  float acc[4][4];
#pragma unroll
  for (int i = 0; i < 4; ++i)
#pragma unroll
    for (int j = 0; j < 4; ++j)
      acc[i][j] = bias ? bias[oo + o4 + j] : 0.0f;

  const int e01 = c0 + c1, e012 = c0 + c1 + c2;
  for (int k0 = 0; k0 < K; k0 += KC) {
    const int kc = min(KC, K - k0);
    __syncthreads();
    for (int e = tid; e < kc * 64; e += 256) {
      int k = e >> 6, o = e & 63;
      Ws[k][o] = Wt[(size_t)(k0 + k) * WOUT + oo + o];
    }
    for (int e = tid; e < kc * 64; e += 256) {
      int k = e >> 6, j = e & 63;
      int c = k0 + k;
      float v;
      if (c < c0)        v = l0 ? s0[(size_t)c * PN + n0 + j]
                                : s0[((size_t)b * c0 + c) * N + nn0 + j];
      else if (c < e01)  { int cc = c - c0;
                           v = l1 ? s1[(size_t)cc * PN + n0 + j]
                                  : s1[((size_t)b * c1 + cc) * N + nn0 + j]; }
      else if (c < e012) { int cc = c - e01;
                           v = l2 ? s2[(size_t)cc * PN + n0 + j]
                                  : s2[((size_t)b * c2 + cc) * N + nn0 + j]; }
      else               { int cc = c - e012;
                           v = l3 ? s3[(size_t)cc * PN + n0 + j]
                                  : s3[((size_t)b * c3 + cc) * N + nn0 + j]; }
      Xs[k][j] = v;
    }
    __syncthreads();
#pragma unroll 2
    for (int k = 0; k < kc; ++k) {
      float4 wv = *(const float4*)&Ws[k][o4];
      float4 xv = *(const float4*)&Xs[k][n4];
      acc[0][0] = fmaf(xv.x, wv.x, acc[0][0]); acc[0][1] = fmaf(xv.x, wv.y, acc[0][1]);
      acc[0][2] = fmaf(xv.x, wv.z, acc[0][2]); acc[0][3] = fmaf(xv.x, wv.w, acc[0][3]);
      acc[1][0] = fmaf(xv.y, wv.x, acc[1][0]); acc[1][1] = fmaf(xv.y, wv.y, acc[1][1]);
      acc[1][2] = fmaf(xv.y, wv.z, acc[1][2]); acc[1][3] = fmaf(xv.y, wv.w, acc[1][3]);
      acc[2][0] = fmaf(xv.z, wv.x, acc[2][0]); acc[2][1] = fmaf(xv.z, wv.y, acc[2][1]);
      acc[2][2] = fmaf(xv.z, wv.z, acc[2][2]); acc[2][3] = fmaf(xv.z, wv.w, acc[2][3]);
      acc[3][0] = fmaf(xv.w, wv.x, acc[3][0]); acc[3][1] = fmaf(xv.w, wv.y, acc[3][1]);
      acc[3][2] = fmaf(xv.w, wv.z, acc[3][2]); acc[3][3] = fmaf(xv.w, wv.w, acc[3][3]);
    }
  }
#pragma unroll
  for (int i = 0; i < 4; ++i) {
    float4 r = make_float4(acc[i][0], acc[i][1], acc[i][2], acc[i][3]);
    *(float4*)&out[(size_t)(n0 + n4 + i) * WOUT + oo + o4] = r;
  }
}

// U and V in one launch: blockIdx.z selects; body is a verbatim copy.
__launch_bounds__(256)
__global__ void projUV_kernel(const float* __restrict__ WtU, const float* __restrict__ WtV,
    const float* __restrict__ ba1, float* __restrict__ Uo, float* __restrict__ Vo,
    int N, int PN,
    const float* __restrict__ feat0, const float* __restrict__ feat1,
    const float* __restrict__ x0, const float* __restrict__ x1)
{
  __shared__ __align__(16) float Ws[KC][68];
  __shared__ __align__(16) float Xs[KC][68];
  const int z = blockIdx.z;
  const float* Wt = z ? WtV : WtU;
  const float* bias = z ? ba1 : 0;
  float* out = z ? Vo : Uo;
  const float* s0 = z ? feat1 : feat0;
  const float* s1 = z ? x1 : x0;
  const int K = 131, WOUT = 128, c0 = 128;
  const int n0 = blockIdx.x * 64;
  const int oo = blockIdx.y * 64;
  const int b = n0 / N;
  const int nn0 = n0 - b * N;
  const int tid = threadIdx.x;
  const int tx = tid & 15, ty = tid >> 4;
  const int o4 = tx * 4, n4 = ty * 4;
  float acc[4][4];
#pragma unroll
  for (int i = 0; i < 4; ++i)
#pragma unroll
    for (int j = 0; j < 4; ++j)
      acc[i][j] = bias ? bias[oo + o4 + j] : 0.0f;

  for (int k0 = 0; k0 < K; k0 += KC) {
    const int kc = min(KC, K - k0);
    __syncthreads();
    for (int e = tid; e < kc * 64; e += 256) {
      int k = e >> 6, o = e & 63;
      Ws[k][o] = Wt[(size_t)(k0 + k) * WOUT + oo + o];
    }
    for (int e = tid; e < kc * 64; e += 256) {
      int k = e >> 6, j = e & 63;
      int c = k0 + k;
      float v;
      if (c < c0) v = s0[((size_t)b * c0 + c) * N + nn0 + j];
      else        v = s1[((size_t)b * 3 + (c - c0)) * N + nn0 + j];
      Xs[k][j] = v;
    }
    __syncthreads();
#pragma unroll 2
    for (int k = 0; k < kc; ++k) {
      float4 wv = *(const float4*)&Ws[k][o4];
      float4 xv = *(const float4*)&Xs[k][n4];
      acc[0][0] = fmaf(xv.x, wv.x, acc[0][0]); acc[0][1] = fmaf(xv.x, wv.y, acc[0][1]);
      acc[0][2] = fmaf(xv.x, wv.z, acc[0][2]); acc[0][3] = fmaf(xv.x, wv.w, acc[0][3]);
      acc[1][0] = fmaf(xv.y, wv.x, acc[1][0]); acc[1][1] = fmaf(xv.y, wv.y, acc[1][1]);
      acc[1][2] = fmaf(xv.y, wv.z, acc[1][2]); acc[1][3] = fmaf(xv.y, wv.w, acc[1][3]);
      acc[2][0] = fmaf(xv.z, wv.x, acc[2][0]); acc[2][1] = fmaf(xv.z, wv.y, acc[2][1]);
      acc[2][2] = fmaf(xv.z, wv.z, acc[2][2]); acc[2][3] = fmaf(xv.z, wv.w, acc[2][3]);
      acc[3][0] = fmaf(xv.w, wv.x, acc[3][0]); acc[3][1] = fmaf(xv.w, wv.y, acc[3][1]);
      acc[3][2] = fmaf(xv.w, wv.z, acc[3][2]); acc[3][3] = fmaf(xv.w, wv.w, acc[3][3]);
    }
  }
#pragma unroll
  for (int i = 0; i < 4; ++i) {
    float4 r = make_float4(acc[i][0], acc[i][1], acc[i][2], acc[i][3]);
    *(float4*)&out[(size_t)(n0 + n4 + i) * WOUT + oo + o4] = r;
  }
}

// --------------------------------------------------------- small proj (G1) ----
__device__ __forceinline__ void seg_accumL(const float* __restrict__ p, int cnt,
    const float* __restrict__ WL, int sC, int sN, long n0, float acc[4])
{
#pragma unroll 4
  for (int c = 0; c < cnt; ++c) {
    float w = WL[c];
    const float* pp = p + (size_t)c * sC + (size_t)n0 * sN;
#pragma unroll
    for (int m = 0; m < 4; ++m)
      acc[m] = fmaf(w, pp[(size_t)m * sN], acc[m]);
  }
}

template<int WP>
__launch_bounds__(256)
__global__ void proj_kernel(
    const float* __restrict__ W0, const float* __restrict__ bias,
    float* __restrict__ out, int OUTS, int wld, int N,
    const float* __restrict__ s0, int c0, int w0,
    const float* __restrict__ s1, int c1, int w1)
{
  __shared__ float Wl[64 * WP];
  const int b = blockIdx.y;
  const int lane = threadIdx.x & 63;
  const int wav = rfl(threadIdx.x >> 6);
  for (int r = wav; r < 64; r += 4)
    for (int c = lane; c < c0; c += 64)
      Wl[r * WP + c] = W0[(size_t)r * wld + w0 + c];
  for (int r = wav; r < 64; r += 4)
    for (int c = lane; c < c1; c += 64)
      Wl[r * WP + c0 + c] = W0[(size_t)r * wld + w1 + c];
  __syncthreads();
  const long n0 = ((long)blockIdx.x * 4 + wav) * 4;
  float bv = bias ? bias[lane] : 0.0f;
  float acc[4] = {bv, bv, bv, bv};
  const float* WL = &Wl[lane * WP];
  seg_accumL(s0 + (size_t)b * c0 * N, c0, WL, N, 1, n0, acc);
  seg_accumL(s1 + (size_t)b * c1 * N, c1, WL + c0, N, 1, n0, acc);
#pragma unroll
  for (int m = 0; m < 4; ++m)
    out[((size_t)b * N + n0 + m) * OUTS + lane] = acc[m];
}

// ------------------------------------------------------------- groupnorm ----
__launch_bounds__(256)
__global__ void gn1_stats_kernel(const float* __restrict__ G1, const float* __restrict__ xyz0,
    const float* __restrict__ fw1, const int* __restrict__ idx0,
    float* __restrict__ stats1, int N)
{
  __shared__ float red[4][4][2];
  int b = blockIdx.y;
  int lane = threadIdx.x & 63, wav = rfl(threadIdx.x >> 6);
  float wg0 = fw1[lane * 6 + 3], wg1 = fw1[lane * 6 + 4], wg2 = fw1[lane * 6 + 5];
  const float* xb = xyz0 + (size_t)b * 3 * N;
  float sum = 0.f, sq = 0.f;
  for (int n = blockIdx.x * 4 + wav; n < N; n += gridDim.x * 4) {
    const int* ip = idx0 + ((size_t)b * N + n) * 16;
    float bx = wg0 * xb[n] + wg1 * xb[N + n] + wg2 * xb[2 * N + n];
#pragma unroll
    for (int k = 0; k < 16; ++k) {
      int m = ip[k];
      float y = G1[((size_t)b * N + m) * 64 + lane] - bx;
      sum += y; sq += y * y;
    }
  }
#pragma unroll
  for (int off = 1; off < 16; off <<= 1) {
    sum += __shfl_xor(sum, off, 64);
    sq += __shfl_xor(sq, off, 64);
  }
  int g = lane >> 4;
  if ((lane & 15) == 0) { red[wav][g][0] = sum; red[wav][g][1] = sq; }
  __syncthreads();
  if (threadIdx.x < 8) {
    int gg = threadIdx.x >> 1, s = threadIdx.x & 1;
    float v = red[0][gg][s] + red[1][gg][s] + red[2][gg][s] + red[3][gg][s];
    atomicAdd(&stats1[(b * 4 + gg) * 2 + s], v);
  }
}

// ------------------------------------------------------------- flow conv2 ----
__launch_bounds__(256, 2)
__global__ void conv2_kernel(const float* __restrict__ G1, const float* __restrict__ xyz0,
    const float* __restrict__ fw1, const int* __restrict__ idx0,
    const float* __restrict__ fw2, const float* __restrict__ fb2,
    const float* __restrict__ fg1, const float* __restrict__ fbe1,
    const float* __restrict__ raw1, float cnt,
    float* __restrict__ y2max, float* __restrict__ y2min,
    float* __restrict__ stats2, int N)
{
  __shared__ __align__(16) float x2[4][16][64];
  __shared__ float red[4][4][2];
  const int b = blockIdx.y;
  const int lane = threadIdx.x & 63;
  const int wav = rfl(threadIdx.x >> 6);
  float4 w[16];
#pragma unroll
  for (int i = 0; i < 16; ++i) w[i] = *(const float4*)&fw2[lane * 64 + i * 4];
  float wg0 = fw1[lane * 6 + 3], wg1 = fw1[lane * 6 + 4], wg2 = fw1[lane * 6 + 5];
  const int g = lane >> 4;
  float s_ = raw1[(b * 4 + g) * 2], q_ = raw1[(b * 4 + g) * 2 + 1];
  float mu1 = s_ / cnt;
  float inv1 = rsqrtf(q_ / cnt - mu1 * mu1 + 1e-5f);
  float sc1 = fg1[lane] * inv1;
  float sh1 = fbe1[lane] - mu1 * sc1;
  float fb2l = fb2[lane];
  const float* xb = xyz0 + (size_t)b * 3 * N;
  float sum = 0.f, sq = 0.f;
  for (int n = blockIdx.x * 4 + wav; n < N; n += gridDim.x * 4) {
    const int* ip = idx0 + ((size_t)b * N + n) * 16;
    float bx = wg0 * xb[n] + wg1 * xb[N + n] + wg2 * xb[2 * N + n];
#pragma unroll
    for (int k = 0; k < 16; ++k) {
      int m = ip[k];
      float y = G1[((size_t)b * N + m) * 64 + lane] - bx;
      x2[wav][k][lane] = leaky(y * sc1 + sh1);
    }
    float acc[16];
#pragma unroll
    for (int k = 0; k < 16; ++k) acc[k] = fb2l;
#pragma unroll
    for (int c4 = 0; c4 < 16; ++c4) {
      float4 w4 = w[c4];
#pragma unroll
      for (int k = 0; k < 16; ++k) {
        float4 x4 = *(const float4*)&x2[wav][k][c4 * 4];
        acc[k] = fmaf(w4.x, x4.x, acc[k]);
        acc[k] = fmaf(w4.y, x4.y, acc[k]);
        acc[k] = fmaf(w4.z, x4.z, acc[k]);
        acc[k] = fmaf(w4.w, x4.w, acc[k]);
      }
    }
    float mx = -3.0e38f, mn = 3.0e38f;
#pragma unroll
    for (int k = 0; k < 16; ++k) {
      mx = fmaxf(mx, acc[k]); mn = fminf(mn, acc[k]);
      sum += acc[k]; sq += acc[k] * acc[k];
    }
    y2max[((size_t)b * N + n) * 64 + lane] = mx;
    y2min[((size_t)b * N + n) * 64 + lane] = mn;
  }
#pragma unroll
  for (int off = 1; off < 16; off <<= 1) {
    sum += __shfl_xor(sum, off, 64);
    sq += __shfl_xor(sq, off, 64);
  }
  if ((lane & 15) == 0) { red[wav][g][0] = sum; red[wav][g][1] = sq; }
  __syncthreads();
  if (threadIdx.x < 8) {
    int gg = threadIdx.x >> 1, s = threadIdx.x & 1;
    float v = red[0][gg][s] + red[1][gg][s] + red[2][gg][s] + red[3][gg][s];
    atomicAdd(&stats2[(b * 4 + gg) * 2 + s], v);
  }
}

__launch_bounds__(256)
__global__ void flow_feat_kernel(const float* __restrict__ y2max, const float* __restrict__ y2min,
    const float* __restrict__ raw2, float cnt,
    const float* __restrict__ fg2, const float* __restrict__ fbe2,
    float* __restrict__ ff_t, int N, int PN)
{
  size_t i = (size_t)blockIdx.x * blockDim.x + threadIdx.x;
  if (i >= (size_t)B_SZ * N * 64) return;
  int c = i & 63;
  size_t pn = i >> 6;
  int b = (int)(pn / N);
  int g = c >> 4;
  float s_ = raw2[(b * 4 + g) * 2], q_ = raw2[(b * 4 + g) * 2 + 1];
  float mu = s_ / cnt;
  float inv = rsqrtf(q_ / cnt - mu * mu + 1e-5f);
  float sc = fg2[c] * inv;
  float sh = fbe2[c] - mu * sc;
  float y = (sc >= 0.0f) ? y2max[i] : y2min[i];
  ff_t[(size_t)c * PN + pn] = leaky(y * sc + sh);
}

// ------------------------------------------------------------------ gates ----
__launch_bounds__(256)
__global__ void gate_zr_kernel(const float* __restrict__ Szr,
    const float* __restrict__ wz, const float* __restrict__ wr,
    const float* __restrict__ xyz0, const float* __restrict__ state,
    const int* __restrict__ idx0,
    float* __restrict__ zo, float* __restrict__ rs_t, int N, int PN)
{
  int b = blockIdx.y;
  int lane = threadIdx.x & 63, wav = rfl(threadIdx.x >> 6);
  float wz0 = wz[lane * 195 + 192], wz1 = wz[lane * 195 + 193], wz2 = wz[lane * 195 + 194];
  float wr0 = wr[lane * 195 + 192], wr1 = wr[lane * 195 + 193], wr2 = wr[lane * 195 + 194];
  const float* xb = xyz0 + (size_t)b * 3 * N;
  for (int n = blockIdx.x * 4 + wav; n < N; n += gridDim.x * 4) {
    const int* ip = idx0 + ((size_t)b * N + n) * 16;
    float u0 = xb[n], u1 = xb[N + n], u2 = xb[2 * N + n];
    float xz = wz0 * u0 + wz1 * u1 + wz2 * u2;
    float xr = wr0 * u0 + wr1 * u1 + wr2 * u2;
    float mz = -3.0e38f, mr = -3.0e38f;
#pragma unroll
    for (int k = 0; k < 16; ++k) {
      size_t mo = ((size_t)b * N + ip[k]) * 128 + lane;
      mz = fmaxf(mz, Szr[mo]);
      mr = fmaxf(mr, Szr[mo + 64]);
    }
    size_t no = ((size_t)b * N + n) * 64 + lane;
    float z = 1.f / (1.f + expf(-(mz - xz)));
    float r = 1.f / (1.f + expf(-(mr - xr)));
    zo[no] = z;
    rs_t[(size_t)lane * PN + (size_t)b * N + n] = r * state[((size_t)b * 64 + lane) * N + n];
  }
}

__launch_bounds__(256)
__global__ void gate_q_ns_kernel(const float* __restrict__ Sq, const float* __restrict__ wq,
    const float* __restrict__ xyz0, const float* __restrict__ zo,
    const float* __restrict__ state, const int* __restrict__ idx0,
    float* __restrict__ ns, int N)
{
  int b = blockIdx.y;
  int lane = threadIdx.x & 63, wav = rfl(threadIdx.x >> 6);
  float wq0 = wq[lane * 195 + 192], wq1 = wq[lane * 195 + 193], wq2 = wq[lane * 195 + 194];
  const float* xb = xyz0 + (size_t)b * 3 * N;
  for (int n = blockIdx.x * 4 + wav; n < N; n += gridDim.x * 4) {
    const int* ip = idx0 + ((size_t)b * N + n) * 16;
    float xq = wq0 * xb[n] + wq1 * xb[N + n] + wq2 * xb[2 * N + n];
    float mq = -3.0e38f;
#pragma unroll
    for (int k = 0; k < 16; ++k)
      mq = fmaxf(mq, Sq[((size_t)b * N + ip[k]) * 64 + lane]);
    size_t no = ((size_t)b * N + n) * 64 + lane;
    float q = tanhf(mq - xq);
    float z = zo[no];
    float st = state[((size_t)b * 64 + lane) * N + n];
    ns[no] = (1.f - z) * st + z * q;
  }
}

// ------------------------------------------------------------------ align ----
// Block: 4 n -> 64 rows (n_loc*16+k). 64x64x128 GEMM, 4x4 micro-tiles.
// Xs XOR-swizzled; Ws = wa2^T in LDS. Softmax over k via shfl_xor(16/32).
__launch_bounds__(256, 2)
__global__ void align_kernel(const float* __restrict__ U, const float* __restrict__ V,
    const float* __restrict__ WtA2, const float* __restrict__ ba2,
    const float* __restrict__ ns, const int* __restrict__ idx1,
    float* __restrict__ out, int N)
{
  __shared__ __align__(16) float Xs[64][128];
  __shared__ __align__(16) float Ws[128][64];
  const int b = blockIdx.y;
  const int tid = threadIdx.x;
  const int lane = tid & 63;
  const int wav = rfl(tid >> 6);

  for (int e = tid; e < 2048; e += 256) {
    int c = e >> 4, o4 = (e & 15) << 2;
    *(float4*)&Ws[c][o4] = *(const float4*)&WtA2[(c << 6) + o4];
  }

  const int n = blockIdx.x * 4 + wav;
  int mkreg = 0;
  {
    const int* ip = idx1 + ((size_t)b * N + n) * 16;
    if (lane < 16) mkreg = ip[lane];
  }
  const int c4l = lane & 31;
  const int half = lane >> 5;
  float4 v4 = *(const float4*)&V[(((size_t)b * N + n) << 7) + (c4l << 2)];
  for (int k0 = 0; k0 < 16; k0 += 2) {
    int k = k0 + half;
    int m = __shfl(mkreg, k);
    float4 u4 = *(const float4*)&U[(((size_t)b * N + m) << 7) + (c4l << 2)];
    float4 xv;
    xv.x = leaky(u4.x + v4.x);
    xv.y = leaky(u4.y + v4.y);
    xv.z = leaky(u4.z + v4.z);
    xv.w = leaky(u4.w + v4.w);
    int row = (wav << 4) + k;
    *(float4*)&Xs[row][(c4l ^ (row & 7)) << 2] = xv;
  }
  __syncthreads();

  const int tx = tid & 15, ty = tid >> 4;
  const int o4 = tx << 2, r0 = ty << 2;
  float4 bav = *(const float4*)&ba2[o4];
  float acc[4][4];
#pragma unroll
  for (int i = 0; i < 4; ++i) {
    acc[i][0] = bav.x; acc[i][1] = bav.y; acc[i][2] = bav.z; acc[i][3] = bav.w;
  }
  for (int c4 = 0; c4 < 32; ++c4) {
    float4 wv0 = *(const float4*)&Ws[c4 * 4 + 0][o4];
    float4 wv1 = *(const float4*)&Ws[c4 * 4 + 1][o4];
    float4 wv2 = *(const float4*)&Ws[c4 * 4 + 2][o4];
    float4 wv3 = *(const float4*)&Ws[c4 * 4 + 3][o4];
#pragma unroll
    for (int i = 0; i < 4; ++i) {
      int row = r0 + i;
      float4 xv = *(const float4*)&Xs[row][(c4 ^ (row & 7)) << 2];
      acc[i][0] = fmaf(xv.x, wv0.x, acc[i][0]);
      acc[i][1] = fmaf(xv.x, wv0.y, acc[i][1]);
      acc[i][2] = fmaf(xv.x, wv0.z, acc[i][2]);
      acc[i][3] = fmaf(xv.x, wv0.w, acc[i][3]);
      acc[i][0] = fmaf(xv.y, wv1.x, acc[i][0]);
      acc[i][1] = fmaf(xv.y, wv1.y, acc[i][1]);
      acc[i][2] = fmaf(xv.y, wv1.z, acc[i][2]);
      acc[i][3] = fmaf(xv.y, wv1.w, acc[i][3]);
      acc[i][0] = fmaf(xv.z, wv2.x, acc[i][0]);
      acc[i][1] = fmaf(xv.z, wv2.y, acc[i][1]);
      acc[i][2] = fmaf(xv.z, wv2.z, acc[i][2]);
      acc[i][3] = fmaf(xv.z, wv2.w, acc[i][3]);
      acc[i][0] = fmaf(xv.w, wv3.x, acc[i][0]);
      acc[i][1] = fmaf(xv.w, wv3.y, acc[i][1]);
      acc[i][2] = fmaf(xv.w, wv3.z, acc[i][2]);
      acc[i][3] = fmaf(xv.w, wv3.w, acc[i][3]);
    }
  }

  float m_[4];
#pragma unroll
  for (int j = 0; j < 4; ++j) {
    float m = fmaxf(fmaxf(acc[0][j], acc[1][j]), fmaxf(acc[2][j], acc[3][j]));
    m = fmaxf(m, __shfl_xor(m, 16, 64));
    m = fmaxf(m, __shfl_xor(m, 32, 64));
    m_[j] = m;
  }
  float e_[4][4], s_[4];
#pragma unroll
  for (int j = 0; j < 4; ++j) {
    float s = 0.f;
#pragma unroll
    for (int i = 0; i < 4; ++i) { e_[i][j] = expf(acc[i][j] - m_[j]); s += e_[i][j]; }
    s += __shfl_xor(s, 16, 64);
    s += __shfl_xor(s, 32, 64);
    s_[j] = s;
  }
  float o_[4] = {0.f, 0.f, 0.f, 0.f};
#pragma unroll
  for (int i = 0; i < 4; ++i) {
    int k = (r0 + i) & 15;
    int m = __shfl(mkreg, k);
    float4 nsv = *(const float4*)&ns[(((size_t)b * N + m) << 6) + o4];
    o_[0] = fmaf(e_[i][0], nsv.x, o_[0]);
    o_[1] = fmaf(e_[i][1], nsv.y, o_[1]);
    o_[2] = fmaf(e_[i][2], nsv.z, o_[2]);
    o_[3] = fmaf(e_[i][3], nsv.w, o_[3]);
  }
#pragma unroll
  for (int j = 0; j < 4; ++j) {
    o_[j] += __shfl_xor(o_[j], 16, 64);
    o_[j] += __shfl_xor(o_[j], 32, 64);
  }
  if ((lane >> 4) == 0) {
#pragma unroll
    for (int j = 0; j < 4; ++j)
      out[((size_t)b * 64 + o4 + j) * N + n] = o_[j] / s_[j];
  }
}

// ------------------------------------------------------------------ launch ----
extern "C" void kernel_launch(void* const* d_in, const int* in_sizes, int n_in,
                              void* d_out, int out_size, void* d_ws, size_t ws_size,
                              hipStream_t stream) {
  (void)n_in; (void)out_size; (void)ws_size;
  const float* xyz0 = (const float*)d_in[0];
  const float* xyz1 = (const float*)d_in[1];
  const float* state = (const float*)d_in[2];
  const float* corr0 = (const float*)d_in[3];
  const float* feat0 = (const float*)d_in[4];
  const float* feat1 = (const float*)d_in[5];
  const float* flow0 = (const float*)d_in[6];
  const float* fw1 = (const float*)d_in[7];
  const float* fb1 = (const float*)d_in[8];
  const float* fg1 = (const float*)d_in[9];
  const float* fbe1 = (const float*)d_in[10];
  const float* fw2 = (const float*)d_in[11];
  const float* fb2 = (const float*)d_in[12];
  const float* fg2 = (const float*)d_in[13];
  const float* fbe2 = (const float*)d_in[14];
  const float* wz = (const float*)d_in[15];
  const float* bz = (const float*)d_in[16];
  const float* wr = (const float*)d_in[17];
  const float* br = (const float*)d_in[18];
  const float* wq = (const float*)d_in[19];
  const float* bq = (const float*)d_in[20];
  const float* wa1 = (const float*)d_in[21];
  const float* ba1 = (const float*)d_in[22];
  const float* wa2 = (const float*)d_in[23];
  const float* ba2 = (const float*)d_in[24];
  float* out = (float*)d_out;

  const int N = in_sizes[0] / (3 * B_SZ);  // 4096
  const int PN = B_SZ * N;                 // 8192
  char* wsb = (char*)d_ws;
  size_t off = 0;
  auto take = [&](size_t bytes) -> char* {
    char* p = wsb + off;
    off += (bytes + 255) & ~(size_t)255;
    return p;
  };
  float* U    = (float*)take((size_t)PN * 128 * 4);
  float* V    = (float*)take((size_t)PN * 128 * 4);
  float* Szr  = (float*)take((size_t)PN * 128 * 4);
  float4* pk0 = (float4*)take((size_t)PN * 4 * 4);
  int*   idx0 = (int*)  take((size_t)PN * 16 * 4);
  int*   idx1 = (int*)  take((size_t)PN * 16 * 4);
  float* G1   = (float*)take((size_t)PN * 64 * 4);
  float* y2mx = (float*)take((size_t)PN * 64 * 4);
  float* y2mn = (float*)take((size_t)PN * 64 * 4);
  float* ff_t = (float*)take((size_t)PN * 64 * 4);
  float* Sq   = (float*)take((size_t)PN * 64 * 4);
  float* zg   = (float*)take((size_t)PN * 64 * 4);
  float* rs_t = (float*)take((size_t)PN * 64 * 4);
  float* ns   = (float*)take((size_t)PN * 64 * 4);
  float* WtZR = (float*)take(195 * 128 * 4);
  float* WtQ  = (float*)take(195 * 64 * 4);
  float* WtU  = (float*)take(131 * 128 * 4);
  float* WtV  = (float*)take(131 * 128 * 4);
  float* WtA2 = (float*)take(128 * 64 * 4);
  float* bZR  = (float*)take(128 * 4);
  float* stats = (float*)take(256);
  float* raw1 = stats, *raw2 = stats + 16;

  const float cntv = 16.0f * N * 16.0f;

  hipMemsetAsync(raw1, 0, 32 * sizeof(float), stream);

  pack_kernel<<<dim3((N + 255) / 256, B_SZ), 256, 0, stream>>>(xyz0, pk0, N);
  prep_w_kernel<<<5, 256, 0, stream>>>(wz, wr, wq, wa1, wa2, bz, br,
      WtZR, WtQ, WtU, WtV, WtA2, bZR);
  knn_wave_kernel<<<dim3(N / 4, B_SZ), 256, 0, stream>>>(pk0, xyz0, idx0, N);
  knn_wave_kernel<<<dim3(N / 4, B_SZ), 256, 0, stream>>>(pk0, xyz1, idx1, N);

  proj_kernel<7><<<dim3(N / 16, B_SZ), 256, 0, stream>>>(
      fw1, fb1, G1, 64, 6, N, flow0, 3, 0, xyz0, 3, 3);

  gn1_stats_kernel<<<dim3(256, B_SZ), 256, 0, stream>>>(G1, xyz0, fw1, idx0, raw1, N);
  conv2_kernel<<<dim3(512, B_SZ), 256, 0, stream>>>(G1, xyz0, fw1, idx0, fw2, fb2, fg1, fbe1,
      raw1, cntv, y2mx, y2mn, raw2, N);
  flow_feat_kernel<<<dim3((unsigned)((size_t)PN * 64 / 256)), 256, 0, stream>>>(
      y2mx, y2mn, raw2, cntv, fg2, fbe2, ff_t, N, PN);

  projT_kernel<<<dim3(PN / 64, 2), 256, 0, stream>>>(WtZR, 195, 128, bZR, Szr, N, PN,
      corr0, 64, 0,  ff_t, 64, 1,  state, 64, 0,  xyz0, 3, 0);

  gate_zr_kernel<<<dim3(256, B_SZ), 256, 0, stream>>>(Szr, wz, wr, xyz0, state, idx0, zg, rs_t, N, PN);

  projT_kernel<<<dim3(PN / 64, 1), 256, 0, stream>>>(WtQ, 195, 64, bq, Sq, N, PN,
      corr0, 64, 0,  ff_t, 64, 1,  rs_t, 64, 1,  xyz0, 3, 0);

  gate_q_ns_kernel<<<dim3(256, B_SZ), 256, 0, stream>>>(Sq, wq, xyz0, zg, state, idx0, ns, N);

  projUV_kernel<<<dim3(PN / 64, 2, 2), 256, 0, stream>>>(WtU, WtV, ba1, U, V, N, PN,
      feat0, feat1, xyz0, xyz1);

  align_kernel<<<dim3(N / 4, B_SZ), 256, 0, stream>>>(U, V, WtA2, ba2, ns, idx1, out, N);
}